// Round 14
// baseline (515.152 us; speedup 1.0000x reference)
//
#include <hip/hip_runtime.h>
#include <math.h>
#include <stdint.h>

#define B_ 2
#define S_ 2048
#define D_ 1024
#define H_ 8
#define NT_ (B_*S_)   // 4096 tokens

static constexpr float LAMBDA_INIT = 0.47071301834358415f;
static constexpr float ONE_MINUS_LI = 1.0f - 0.47071301834358415f;

typedef __attribute__((ext_vector_type(8))) short bf16x8;
typedef __attribute__((ext_vector_type(4))) float f32x4;

__device__ __forceinline__ unsigned short f2bf(float x) {
    union { float f; unsigned int u; } v; v.f = x;
    unsigned int r = v.u + 0x7fffu + ((v.u >> 16) & 1u);
    return (unsigned short)(r >> 16);
}
__device__ __forceinline__ float bf2f(unsigned short b) {
    union { unsigned int u; float f; } v; v.u = ((unsigned int)b) << 16;
    return v.f;
}

#define GLD16(gp, lp) __builtin_amdgcn_global_load_lds( \
    (const __attribute__((address_space(1))) void*)(gp), \
    (__attribute__((address_space(3))) void*)(lp), 16, 0, 0)

// ---------------------------------------------------------------- lam scalar
__global__ void lam_kernel(const float* __restrict__ lq1, const float* __restrict__ lk1,
                           const float* __restrict__ lq2, const float* __restrict__ lk2,
                           float* __restrict__ lam_out) {
    int t = threadIdx.x;  // 64 threads
    float p1 = lq1[t] * lk1[t];
    float p2 = lq2[t] * lk2[t];
    for (int off = 32; off; off >>= 1) {
        p1 += __shfl_xor(p1, off);
        p2 += __shfl_xor(p2, off);
    }
    if (t == 0) lam_out[0] = expf(p1) - expf(p2) + LAMBDA_INIT;
}

// ------------------------------------------ fused prep: 4 weight transposes + x convert
__global__ __launch_bounds__(256) void prep_kernel(const float* __restrict__ x,
                                                   const float* __restrict__ w_qkv,
                                                   const float* __restrict__ w_out,
                                                   const float* __restrict__ w1,
                                                   const float* __restrict__ w2,
                                                   short* __restrict__ x_bf,
                                                   short* __restrict__ w_qkvT,
                                                   short* __restrict__ w_outT,
                                                   short* __restrict__ w1T,
                                                   short* __restrict__ w2T) {
    const int z = blockIdx.x;
    if (z >= 12288) {   // convert x
        const size_t i = ((size_t)(z - 12288) * 256 + threadIdx.x) * 4;
        float4 v = *(const float4*)(x + i);
        *(ushort4*)(x_bf + i) = make_ushort4(f2bf(v.x), f2bf(v.y), f2bf(v.z), f2bf(v.w));
        return;
    }
    const float* W; short* WT; int K, N, zz;
    if (z < 3072)      { W = w_qkv; WT = w_qkvT; K = 1024; N = 3072; zz = z; }
    else if (z < 4096) { W = w_out; WT = w_outT; K = 1024; N = 1024; zz = z - 3072; }
    else if (z < 8192) { W = w1;    WT = w1T;    K = 1024; N = 4096; zz = z - 4096; }
    else               { W = w2;    WT = w2T;    K = 4096; N = 1024; zz = z - 8192; }
    const int nx = N >> 5;
    const int bx = zz % nx, by = zz / nx;
    __shared__ float tile[32][33];
    const int t = threadIdx.x;
    const int k0 = by * 32, n0 = bx * 32;
    const int r = t >> 3, c0 = (t & 7) * 4;
    float4 v = *(const float4*)(W + (size_t)(k0 + r) * N + n0 + c0);
    tile[r][c0 + 0] = v.x; tile[r][c0 + 1] = v.y;
    tile[r][c0 + 2] = v.z; tile[r][c0 + 3] = v.w;
    __syncthreads();
    ushort4 o = make_ushort4(f2bf(tile[c0 + 0][r]), f2bf(tile[c0 + 1][r]),
                             f2bf(tile[c0 + 2][r]), f2bf(tile[c0 + 3][r]));
    *(ushort4*)(WT + (size_t)(n0 + r) * K + k0 + c0) = o;
}

// --------------------------------------------- V transpose: qkv V part -> vt[bh][e][s]
__global__ __launch_bounds__(256) void vtrans_kernel(const short* __restrict__ qkv_bf,
                                                     short* __restrict__ vt) {
    __shared__ short tile[32][34];
    const int s0 = blockIdx.x * 32, e0 = blockIdx.y * 32, bh = blockIdx.z;
    const int b = bh >> 3, h = bh & 7;
    const int t = threadIdx.x, r = t >> 3, c0 = (t & 7) * 4;
    ushort4 v = *(const ushort4*)(qkv_bf + (size_t)(b * S_ + s0 + r) * 3072 + 2048 + h * 128 + e0 + c0);
    tile[r][c0 + 0] = v.x; tile[r][c0 + 1] = v.y;
    tile[r][c0 + 2] = v.z; tile[r][c0 + 3] = v.w;
    __syncthreads();
    ushort4 o = make_ushort4((unsigned short)tile[c0 + 0][r], (unsigned short)tile[c0 + 1][r],
                             (unsigned short)tile[c0 + 2][r], (unsigned short)tile[c0 + 3][r]);
    *(ushort4*)(vt + ((size_t)bh * 128 + e0 + r) * S_ + s0 + c0) = o;
}

// ---------------------------------------------------------------- bf16 MFMA GEMM
// C = A @ BT^T. 128x128 tile, BK=32, 4 waves, 4x4 16x16 frags/wave.
// T4 pipeline: 3 LDS buffers, counted vmcnt(4), raw s_barrier. T2 source-side swizzle.
template <int EPI, int OUTBF, int SPLITK>
__global__ __launch_bounds__(256) void gemm_bt(const short* __restrict__ A,
                                               const short* __restrict__ BT,
                                               const float* __restrict__ bias,
                                               void* __restrict__ C0,
                                               void* __restrict__ C1,
                                               int M, int N, int Kfull, int Ksub) {
    __shared__ short As[3][128 * 32];
    __shared__ short Bs[3][128 * 32];
    const int t = threadIdx.x;
    const int w = t >> 6, l = t & 63;
    const int lr = l & 15, lg = l >> 4;

    // block remap: XCD-contiguous virtual index, split-K decode, shaped chunk
    const int GX = gridDim.x;
    const int nwg = GX * gridDim.y;
    int flat = blockIdx.y * GX + blockIdx.x;
    flat = (flat & 7) * (nwg >> 3) + (flat >> 3);      // XCD-contiguous
    int part = 0;
    if (SPLITK) { const int per = nwg >> 1; part = flat / per; flat = flat % per; }
    const int per_part = SPLITK ? (nwg >> 1) : nwg;
    const int GYp = per_part / GX;
    const int panel = flat / (8 * GYp);
    const int idx = flat % (8 * GYp);
    const int by = idx >> 3;
    const int bx = panel * 8 + (idx & 7);
    const int row0 = by * 128, col0 = bx * 128;
    const int wr = (w >> 1) * 64, wc = (w & 1) * 64;

    f32x4 acc[4][4];
#pragma unroll
    for (int i = 0; i < 4; ++i)
#pragma unroll
        for (int j = 0; j < 4; ++j) acc[i][j] = (f32x4){0.f, 0.f, 0.f, 0.f};

    // T2: pre-swizzled global k-slot (involution keyed on row bits 1-2 = (l>>3)&3)
    const int sg = ((l & 3) ^ ((l >> 3) & 3)) * 8;
    const short* Ag = A + (size_t)part * Ksub + (size_t)(row0 + w * 32 + (l >> 2)) * Kfull + sg;
    const short* Bg = BT + (size_t)part * Ksub + (size_t)(col0 + w * 32 + (l >> 2)) * Kfull + sg;

    const int nst = Ksub >> 5;

    auto stage = [&](int T, int Bf) {
#pragma unroll
        for (int j = 0; j < 2; ++j) {
            GLD16(Ag + (T << 5) + (size_t)j * 16 * Kfull, &As[Bf][(w * 2 + j) * 512]);
            GLD16(Bg + (T << 5) + (size_t)j * 16 * Kfull, &Bs[Bf][(w * 2 + j) * 512]);
        }
    };

    // prologue: tiles 0 and 1 in flight (8 loads/wave outstanding)
    stage(0, 0);
    stage(1, 1);

    // T2: swizzled read slot (per-lane constant)
    const int rslot = (lg ^ ((lr >> 1) & 3)) * 8;

    int cur = 0;
    for (int k = 0; k < nst; ++k) {
        if (k + 1 < nst) {
            asm volatile("s_waitcnt vmcnt(4)" ::: "memory");
        } else {
            asm volatile("s_waitcnt vmcnt(0)" ::: "memory");
        }
        __builtin_amdgcn_s_barrier();
        __builtin_amdgcn_sched_barrier(0);
        const int nk = k + 2;
        if (nk < nst) {
            int nb = cur + 2; if (nb >= 3) nb -= 3;
            stage(nk, nb);
        }
        bf16x8 af[4], bfr[4];
#pragma unroll
        for (int i = 0; i < 4; ++i)
            af[i] = *(const bf16x8*)(&As[cur][(wr + i * 16 + lr) * 32 + rslot]);
#pragma unroll
        for (int j = 0; j < 4; ++j)
            bfr[j] = *(const bf16x8*)(&Bs[cur][(wc + j * 16 + lr) * 32 + rslot]);
#pragma unroll
        for (int i = 0; i < 4; ++i)
#pragma unroll
            for (int j = 0; j < 4; ++j)
                acc[i][j] = __builtin_amdgcn_mfma_f32_16x16x32_bf16(af[i], bfr[j], acc[i][j], 0, 0, 0);
        __builtin_amdgcn_sched_barrier(0);
        asm volatile("s_waitcnt lgkmcnt(0)" ::: "memory");
        cur = (cur + 1 == 3) ? 0 : cur + 1;
    }

    void* Cout = (SPLITK && part) ? C1 : C0;
#pragma unroll
    for (int i = 0; i < 4; ++i) {
#pragma unroll
        for (int j = 0; j < 4; ++j) {
            const int col = col0 + wc + j * 16 + lr;
            float bcol = (EPI >= 1) ? bias[col] : 0.f;
#pragma unroll
            for (int r = 0; r < 4; ++r) {
                const int row = row0 + wr + i * 16 + lg * 4 + r;
                float v = acc[i][j][r];
                if (EPI >= 1) v += bcol;
                if (EPI == 2) v = v / (1.0f + expf(-v));
                if (OUTBF) ((short*)Cout)[(size_t)row * N + col] = (short)f2bf(v);
                else       ((float*)Cout)[(size_t)row * N + col] = v;
            }
        }
    }
}

// ------------------------------------------------- RoPE + split + q2/k2 RMSNorm (bf16 io)
__global__ __launch_bounds__(256) void rope_kernel(const short* __restrict__ qkv,
                                                   const float* __restrict__ sigmas,
                                                   const float* __restrict__ lnq_w,
                                                   const float* __restrict__ lnq_b,
                                                   short* __restrict__ q1, short* __restrict__ q2n,
                                                   short* __restrict__ k1, short* __restrict__ k2n) {
    const int tok = blockIdx.x;            // 0..4095
    const int b = tok >> 11, s = tok & 2047;
    const int t = threadIdx.x;
    const int hh = t >> 4;                 // 0..15 (head in 2H layout)
    const int d0 = (t & 15) * 4;

    const short* qrow = qkv + (size_t)tok * 3072 + hh * 64 + d0;
    ushort4 qv = *(const ushort4*)qrow;
    ushort4 kv = *(const ushort4*)(qrow + 1024);
    float q[4] = {bf2f(qv.x), bf2f(qv.y), bf2f(qv.z), bf2f(qv.w)};
    float k[4] = {bf2f(kv.x), bf2f(kv.y), bf2f(kv.z), bf2f(kv.w)};

    if (d0 < 32) {
#pragma unroll
        for (int pr = 0; pr < 2; ++pr) {
            const int i = d0 / 2 + pr;
            float freq = (float)s * powf(10000.0f, -(float)i / 16.0f);
            float sn, c;
            sincosf(freq, &sn, &c);
            float x0 = q[2 * pr], x1 = q[2 * pr + 1];
            q[2 * pr]     = x0 * c - x1 * sn;
            q[2 * pr + 1] = x1 * c + x0 * sn;
            x0 = k[2 * pr]; x1 = k[2 * pr + 1];
            k[2 * pr]     = x0 * c - x1 * sn;
            k[2 * pr + 1] = x1 * c + x0 * sn;
        }
    }

    const int h = hh >> 1, j = hh & 1;
    const size_t obase = ((size_t)(b * H_ + h) * S_ + s) * 64 + d0;
    if (j == 0) {
        *(ushort4*)&q1[obase] = make_ushort4(f2bf(q[0]), f2bf(q[1]), f2bf(q[2]), f2bf(q[3]));
        *(ushort4*)&k1[obase] = make_ushort4(f2bf(k[0]), f2bf(k[1]), f2bf(k[2]), f2bf(k[3]));
    } else {
        float ssq_q = 0.f, ssq_k = 0.f;
#pragma unroll
        for (int i = 0; i < 4; ++i) {
            const float sg = sigmas[b * 64 + d0 + i];
            q[i] += sg; k[i] += sg;
            ssq_q += q[i] * q[i];
            ssq_k += k[i] * k[i];
        }
        for (int off = 1; off < 16; off <<= 1) {
            ssq_q += __shfl_xor(ssq_q, off, 16);
            ssq_k += __shfl_xor(ssq_k, off, 16);
        }
        const float rq = rsqrtf(ssq_q / 64.0f + 1e-8f);
        const float rk = rsqrtf(ssq_k / 64.0f + 1e-8f);
        float oq[4], ok[4];
#pragma unroll
        for (int i = 0; i < 4; ++i) {
            const float w = lnq_w[d0 + i], bb = lnq_b[d0 + i];
            oq[i] = q[i] * rq * w + bb;
            ok[i] = k[i] * rk * w + bb;
        }
        *(ushort4*)&q2n[obase] = make_ushort4(f2bf(oq[0]), f2bf(oq[1]), f2bf(oq[2]), f2bf(oq[3]));
        *(ushort4*)&k2n[obase] = make_ushort4(f2bf(ok[0]), f2bf(ok[1]), f2bf(ok[2]), f2bf(ok[3]));
    }
}

// ------------------------------------------------- softmax update (per wave, one branch)
// T13 defer-rescale: skip O-rescale when running max grows <= 8 (P bounded by e^8).
__device__ __forceinline__ void sm_update(f32x4 (&s)[4], float (&m)[4], float (&lsum)[4],
                                          f32x4 (&o)[8], short* __restrict__ Pw,
                                          const bool diag, const int qr0, const int k0,
                                          const int lr, const int lg) {
    float nm[4];
#pragma unroll
    for (int r = 0; r < 4; ++r) nm[r] = m[r];
#pragma unroll
    for (int ks = 0; ks < 4; ++ks) {
#pragma unroll
        for (int r = 0; r < 4; ++r) {
            float v = s[ks][r];
            if (diag && (k0 + ks * 16 + lr > qr0 + r)) v = -INFINITY;
            else v *= 0.125f;
            s[ks][r] = v;
            nm[r] = fmaxf(nm[r], v);
        }
    }
#pragma unroll
    for (int r = 0; r < 4; ++r) {
        nm[r] = fmaxf(nm[r], __shfl_xor(nm[r], 1));
        nm[r] = fmaxf(nm[r], __shfl_xor(nm[r], 2));
        nm[r] = fmaxf(nm[r], __shfl_xor(nm[r], 4));
        nm[r] = fmaxf(nm[r], __shfl_xor(nm[r], 8));
    }
    bool grow = false;
#pragma unroll
    for (int r = 0; r < 4; ++r) grow = grow || (nm[r] > m[r] + 8.0f);
    if (__any(grow)) {
        float al[4];
#pragma unroll
        for (int r = 0; r < 4; ++r) {
            al[r] = __expf(m[r] - nm[r]);
            m[r] = nm[r];
            lsum[r] *= al[r];
        }
#pragma unroll
        for (int es = 0; es < 8; ++es) {
#pragma unroll
            for (int r = 0; r < 4; ++r) o[es][r] *= al[r];
        }
    }
    float rs[4] = {0.f, 0.f, 0.f, 0.f};
#pragma unroll
    for (int ks = 0; ks < 4; ++ks) {
#pragma unroll
        for (int r = 0; r < 4; ++r) {
            float p = __expf(s[ks][r] - m[r]);
            rs[r] += p;
            Pw[(lg * 4 + r) * 72 + ks * 16 + lr] = (short)f2bf(p);
        }
    }
#pragma unroll
    for (int r = 0; r < 4; ++r) {
        rs[r] += __shfl_xor(rs[r], 1);
        rs[r] += __shfl_xor(rs[r], 2);
        rs[r] += __shfl_xor(rs[r], 4);
        rs[r] += __shfl_xor(rs[r], 8);
        lsum[r] += rs[r];
    }
}

// ------------------------------------------------- dual attention, split-K partials
// 1024 blocks x 256 threads (4 waves). QBLK=64, KVBLK=64. XCD-swizzled (2 bh/XCD).
// V^T read DIRECTLY from global (L2-resident ~1MB/XCD thanks to bh pinning) —
// no V staging, no barrier dependency on V. LDS 28KB -> 4 blocks/CU = 16 waves/CU.
__global__ __launch_bounds__(256, 4) void attn_part(const short* __restrict__ q1g,
                                                    const short* __restrict__ q2g,
                                                    const short* __restrict__ k1g,
                                                    const short* __restrict__ k2g,
                                                    const short* __restrict__ vt,
                                                    short* __restrict__ pO0,
                                                    short* __restrict__ pO1,
                                                    float* __restrict__ pml) {
    __shared__ short Ks1[64 * 72];
    __shared__ short Ks2[64 * 72];
    __shared__ short Ps[4][16 * 72];   // per-wave P (reused across branches)

    const int i = blockIdx.x;            // 0..1023
    const int xcd = i & 7;
    const int slot = i >> 3;             // 0..127
    const int a = slot >> 6;             // bh within xcd
    const int j = slot & 63;
    const int qt = 31 - (j >> 1);        // LPT: big first
    const int part = j & 1;
    const int bh = xcd * 2 + a;
    const int q0 = qt * 64;
    const int t = threadIdx.x, w = t >> 6, l = t & 63;
    const int lr = l & 15, lg = l >> 4;

    const size_t kbase = (size_t)bh * S_ * 64;
    const size_t vbase = (size_t)bh * 128 * S_;

    // Q fragments (wave w owns rows q0 + w*16 .. +15)
    bf16x8 qa1[2], qa2[2];
    {
        const size_t rb = kbase + (size_t)(q0 + w * 16 + lr) * 64;
#pragma unroll
        for (int dh = 0; dh < 2; ++dh) {
            qa1[dh] = *(const bf16x8*)(q1g + rb + dh * 32 + lg * 8);
            qa2[dh] = *(const bf16x8*)(q2g + rb + dh * 32 + lg * 8);
        }
    }

    const int nkt = qt + 1, mid = (nkt + 1) >> 1;
    const int kt0 = part ? mid : 0, kt1 = part ? nkt : mid;

    float m1[4], m2[4], l1[4], l2[4];
#pragma unroll
    for (int r = 0; r < 4; ++r) { m1[r] = -1e30f; m2[r] = -1e30f; l1[r] = 0.f; l2[r] = 0.f; }
    f32x4 o1[8], o2[8];
#pragma unroll
    for (int es = 0; es < 8; ++es) { o1[es] = (f32x4){0.f,0.f,0.f,0.f}; o2[es] = (f32x4){0.f,0.f,0.f,0.f}; }

    short* Pw = &Ps[w][0];
    const int qr0 = q0 + w * 16 + lg * 4;
    const int wrow_lo = q0 + w * 16;

    const int sr = t >> 2, sc = (t & 3) * 16;   // K staging: 64 rows x 16 elems

    for (int kt = kt0; kt < kt1; ++kt) {
        const int k0 = kt * 64;
        __syncthreads();   // prior tile reads done
        // stage K1,K2 [64][72] (vectorized 16B, coalesced)
        {
            const size_t g = kbase + (size_t)(k0 + sr) * 64 + sc;
            *(bf16x8*)(Ks1 + sr * 72 + sc)     = *(const bf16x8*)(k1g + g);
            *(bf16x8*)(Ks1 + sr * 72 + sc + 8) = *(const bf16x8*)(k1g + g + 8);
            *(bf16x8*)(Ks2 + sr * 72 + sc)     = *(const bf16x8*)(k2g + g);
            *(bf16x8*)(Ks2 + sr * 72 + sc + 8) = *(const bf16x8*)(k2g + g + 8);
        }
        __syncthreads();

        const bool diag = (k0 + 63 > wrow_lo);
        const short* vtile = vt + vbase + k0;

        // ---- branch 1
        {
            f32x4 s[4];
#pragma unroll
            for (int ks = 0; ks < 4; ++ks) s[ks] = (f32x4){0.f,0.f,0.f,0.f};
            __builtin_amdgcn_s_setprio(1);
#pragma unroll
            for (int ks = 0; ks < 4; ++ks)
#pragma unroll
                for (int dh = 0; dh < 2; ++dh) {
                    bf16x8 kf = *(const bf16x8*)(Ks1 + (ks * 16 + lr) * 72 + dh * 32 + lg * 8);
                    s[ks] = __builtin_amdgcn_mfma_f32_16x16x32_bf16(qa1[dh], kf, s[ks], 0, 0, 0);
                }
            __builtin_amdgcn_s_setprio(0);
            sm_update(s, m1, l1, o1, Pw, diag, qr0, k0, lr, lg);
            __builtin_amdgcn_s_setprio(1);
#pragma unroll
            for (int kb = 0; kb < 2; ++kb) {
                bf16x8 pf = *(const bf16x8*)(Pw + lr * 72 + kb * 32 + lg * 8);
#pragma unroll
                for (int es = 0; es < 8; ++es) {
                    bf16x8 vf = *(const bf16x8*)(vtile + (size_t)(es * 16 + lr) * S_ + kb * 32 + lg * 8);
                    o1[es] = __builtin_amdgcn_mfma_f32_16x16x32_bf16(pf, vf, o1[es], 0, 0, 0);
                }
            }
            __builtin_amdgcn_s_setprio(0);
        }
        // ---- branch 2
        {
            f32x4 s[4];
#pragma unroll
            for (int ks = 0; ks < 4; ++ks) s[ks] = (f32x4){0.f,0.f,0.f,0.f};
            __builtin_amdgcn_s_setprio(1);
#pragma unroll
            for (int ks = 0; ks < 4; ++ks)
#pragma unroll
                for (int dh = 0; dh < 2; ++dh) {
                    bf16x8 kf = *(const bf16x8*)(Ks2 + (ks * 16 + lr) * 72 + dh * 32 + lg * 8);
                    s[ks] = __builtin_amdgcn_mfma_f32_16x16x32_bf16(qa2[dh], kf, s[ks], 0, 0, 0);
                }
            __builtin_amdgcn_s_setprio(0);
            sm_update(s, m2, l2, o2, Pw, diag, qr0, k0, lr, lg);
            __builtin_amdgcn_s_setprio(1);
#pragma unroll
            for (int kb = 0; kb < 2; ++kb) {
                bf16x8 pf = *(const bf16x8*)(Pw + lr * 72 + kb * 32 + lg * 8);
#pragma unroll
                for (int es = 0; es < 8; ++es) {
                    bf16x8 vf = *(const bf16x8*)(vtile + (size_t)(es * 16 + lr) * S_ + kb * 32 + lg * 8);
                    o2[es] = __builtin_amdgcn_mfma_f32_16x16x32_bf16(pf, vf, o2[es], 0, 0, 0);
                }
            }
            __builtin_amdgcn_s_setprio(0);
        }
    }

    // store partials: packed 2xbf16 uints, wave-fragment layout, fully coalesced.
    {
        uint32_t* pO = (uint32_t*)(part ? pO1 : pO0);
        const size_t wb = (((size_t)bh * 32 + qt) * 4 + w) * 2048;
#pragma unroll
        for (int r = 0; r < 4; ++r) {
#pragma unroll
            for (int u = 0; u < 4; ++u) {
                uint32_t v1 = (uint32_t)f2bf(o1[2 * u][r]) | ((uint32_t)f2bf(o1[2 * u + 1][r]) << 16);
                pO[wb + (size_t)((r * 2 + 0) * 4 + u) * 64 + l] = v1;
                uint32_t v2 = (uint32_t)f2bf(o2[2 * u][r]) | ((uint32_t)f2bf(o2[2 * u + 1][r]) << 16);
                pO[wb + (size_t)((r * 2 + 1) * 4 + u) * 64 + l] = v2;
            }
        }
    }
    if (lr == 0) {
#pragma unroll
        for (int r = 0; r < 4; ++r) {
            const int q = q0 + w * 16 + lg * 4 + r;
            float4 v = make_float4(m1[r], l1[r], m2[r], l2[r]);
            *(float4*)&pml[(((size_t)part * 16 + bh) * S_ + q) * 4] = v;
        }
    }
}

// ------------------------------------------------- combine partials + diff + RMSNorm
__global__ __launch_bounds__(256) void attn_combine(const short* __restrict__ pO0,
                                                    const short* __restrict__ pO1,
                                                    const float* __restrict__ pml,
                                                    const float* __restrict__ lamp,
                                                    const float* __restrict__ ln_w,
                                                    const float* __restrict__ ln_b,
                                                    short* __restrict__ arms) {
    const int tok = blockIdx.x;           // 0..4095
    const int b = tok >> 11, q = tok & 2047;
    const int t = threadIdx.x;
    const int h = t >> 5, ln32 = t & 31, e0 = ln32 * 4;
    const int bh = b * H_ + h;
    const float lam = lamp[0];

    float4 mla = *(const float4*)&pml[(((size_t)0 * 16 + bh) * S_ + q) * 4];
    float4 mlb = *(const float4*)&pml[(((size_t)1 * 16 + bh) * S_ + q) * 4];

    const float m1 = fmaxf(mla.x, mlb.x);
    const float aa1 = __expf(mla.x - m1), ab1 = __expf(mlb.x - m1);
    const float il1 = 1.0f / (aa1 * mla.y + ab1 * mlb.y);
    const float m2 = fmaxf(mla.z, mlb.z);
    const float aa2 = __expf(mla.z - m2), ab2 = __expf(mlb.z - m2);
    const float il2 = 1.0f / (aa2 * mla.w + ab2 * mlb.w);

    // decode packed wave-fragment layout (QBLK=64: qt=q>>6, w=(q>>4)&3)
    const int qt = q >> 6, w = (q >> 4) & 3, lg = (q >> 2) & 3, r = q & 3;
    const int es = ln32 >> 2, u = es >> 1, half = es & 1;
    const int lane0 = lg * 16 + (ln32 & 3) * 4;
    const size_t wb = (((size_t)bh * 32 + qt) * 4 + w) * 2048;
    const uint32_t* P0 = (const uint32_t*)pO0;
    const uint32_t* P1 = (const uint32_t*)pO1;
    const uint4 a1  = *(const uint4*)&P0[wb + (size_t)((r * 2 + 0) * 4 + u) * 64 + lane0];
    const uint4 b1v = *(const uint4*)&P1[wb + (size_t)((r * 2 + 0) * 4 + u) * 64 + lane0];
    const uint4 a2  = *(const uint4*)&P0[wb + (size_t)((r * 2 + 1) * 4 + u) * 64 + lane0];
    const uint4 b2v = *(const uint4*)&P1[wb + (size_t)((r * 2 + 1) * 4 + u) * 64 + lane0];
    const int sh = 16 * half;

    float comb[4]; float ssq = 0.f;
    {
        const uint32_t aw1[4] = {a1.x, a1.y, a1.z, a1.w};
        const uint32_t bw1[4] = {b1v.x, b1v.y, b1v.z, b1v.w};
        const uint32_t aw2[4] = {a2.x, a2.y, a2.z, a2.w};
        const uint32_t bw2[4] = {b2v.x, b2v.y, b2v.z, b2v.w};
#pragma unroll
        for (int i = 0; i < 4; ++i) {
            const float O1 = (aa1 * bf2f((unsigned short)(aw1[i] >> sh)) +
                              ab1 * bf2f((unsigned short)(bw1[i] >> sh))) * il1;
            const float O2 = (aa2 * bf2f((unsigned short)(aw2[i] >> sh)) +
                              ab2 * bf2f((unsigned short)(bw2[i] >> sh))) * il2;
            const float c = O1 - lam * O2;
            comb[i] = c; ssq += c * c;
        }
    }
    for (int off = 1; off < 32; off <<= 1) ssq += __shfl_xor(ssq, off, 32);
    const float rms = rsqrtf(ssq / 128.0f + 1e-8f);

    ushort4 o;
    unsigned short* op = (unsigned short*)&o;
#pragma unroll
    for (int i = 0; i < 4; ++i) {
        const int e = e0 + i;
        op[i] = f2bf((comb[i] * rms * ln_w[e] + ln_b[e]) * ONE_MINUS_LI);
    }
    *(ushort4*)&arms[(size_t)tok * 1024 + h * 128 + e0] = o;
}

// -------------------------- add_ln1: h_bf = bf16( LN(a0 + a1 + x) )
__global__ __launch_bounds__(256) void add_ln1_kernel(const float* __restrict__ A0,
                                                      const float* __restrict__ A1,
                                                      const float* __restrict__ X,
                                                      const float* __restrict__ w,
                                                      const float* __restrict__ bvec,
                                                      short* __restrict__ out_bf) {
    const int row = blockIdx.x;
    const int t = threadIdx.x;
    __shared__ float red[4];

    float4 a0 = *(const float4*)&A0[(size_t)row * 1024 + t * 4];
    float4 a1 = *(const float4*)&A1[(size_t)row * 1024 + t * 4];
    float4 xv = *(const float4*)&X[(size_t)row * 1024 + t * 4];
    float v[4] = {a0.x + a1.x + xv.x, a0.y + a1.y + xv.y,
                  a0.z + a1.z + xv.z, a0.w + a1.w + xv.w};

    float s = v[0] + v[1] + v[2] + v[3];
    for (int off = 1; off < 64; off <<= 1) s += __shfl_xor(s, off);
    if ((t & 63) == 0) red[t >> 6] = s;
    __syncthreads();
    const float mean = (red[0] + red[1] + red[2] + red[3]) * (1.0f / 1024.0f);

    float sq = 0.f;
#pragma unroll
    for (int i = 0; i < 4; ++i) { const float d = v[i] - mean; sq += d * d; }
    __syncthreads();
    for (int off = 1; off < 64; off <<= 1) sq += __shfl_xor(sq, off);
    if ((t & 63) == 0) red[t >> 6] = sq;
    __syncthreads();
    const float var = (red[0] + red[1] + red[2] + red[3]) * (1.0f / 1024.0f);
    const float rstd = rsqrtf(var + 1e-5f);

    ushort4 o;
    unsigned short* op = (unsigned short*)&o;
#pragma unroll
    for (int i = 0; i < 4; ++i)
        op[i] = f2bf((v[i] - mean) * rstd * w[t * 4 + i] + bvec[t * 4 + i]);
    *(ushort4*)&out_bf[(size_t)row * 1024 + t * 4] = o;
}

// -------------------------- add_ln2: out = LN(f0 + f1 + bias + h_bf)  (f32 out)
__global__ __launch_bounds__(256) void add_ln2_kernel(const float* __restrict__ F0,
                                                      const float* __restrict__ F1,
                                                      const float* __restrict__ bias,
                                                      const short* __restrict__ Hbf,
                                                      const float* __restrict__ w,
                                                      const float* __restrict__ bvec,
                                                      float* __restrict__ out) {
    const int row = blockIdx.x;
    const int t = threadIdx.x;
    __shared__ float red[4];

    float4 f0 = *(const float4*)&F0[(size_t)row * 1024 + t * 4];
    float4 f1 = *(const float4*)&F1[(size_t)row * 1024 + t * 4];
    float4 bv = *(const float4*)&bias[t * 4];
    ushort4 hv = *(const ushort4*)&Hbf[(size_t)row * 1024 + t * 4];
    float v[4] = {f0.x + f1.x + bv.x + bf2f(hv.x), f0.y + f1.y + bv.y + bf2f(hv.y),
                  f0.z + f1.z + bv.z + bf2f(hv.z), f0.w + f1.w + bv.w + bf2f(hv.w)};

    float s = v[0] + v[1] + v[2] + v[3];
    for (int off = 1; off < 64; off <<= 1) s += __shfl_xor(s, off);
    if ((t & 63) == 0) red[t >> 6] = s;
    __syncthreads();
    const float mean = (red[0] + red[1] + red[2] + red[3]) * (1.0f / 1024.0f);

    float sq = 0.f;
#pragma unroll
    for (int i = 0; i < 4; ++i) { const float d = v[i] - mean; sq += d * d; }
    __syncthreads();
    for (int off = 1; off < 64; off <<= 1) sq += __shfl_xor(sq, off);
    if ((t & 63) == 0) red[t >> 6] = sq;
    __syncthreads();
    const float var = (red[0] + red[1] + red[2] + red[3]) * (1.0f / 1024.0f);
    const float rstd = rsqrtf(var + 1e-5f);

    float o[4];
#pragma unroll
    for (int i = 0; i < 4; ++i)
        o[i] = (v[i] - mean) * rstd * w[t * 4 + i] + bvec[t * 4 + i];
    *(float4*)&out[(size_t)row * 1024 + t * 4] = make_float4(o[0], o[1], o[2], o[3]);
}

// ---------------------------------------------------------------- launch
extern "C" void kernel_launch(void* const* d_in, const int* in_sizes, int n_in,
                              void* d_out, int out_size, void* d_ws, size_t ws_size,
                              hipStream_t stream) {
    const float* x      = (const float*)d_in[0];
    const float* sigmas = (const float*)d_in[1];
    const float* w_qkv  = (const float*)d_in[2];
    const float* w_out  = (const float*)d_in[3];
    const float* lq1    = (const float*)d_in[4];
    const float* lk1    = (const float*)d_in[5];
    const float* lq2    = (const float*)d_in[6];
    const float* lk2    = (const float*)d_in[7];
    const float* ln_w   = (const float*)d_in[8];
    const float* ln_b   = (const float*)d_in[9];
    const float* lnq_w  = (const float*)d_in[10];
    const float* lnq_b  = (const float*)d_in[11];
    const float* ln1_w  = (const float*)d_in[12];
    const float* ln1_b  = (const float*)d_in[13];
    const float* ln2_w  = (const float*)d_in[14];
    const float* ln2_b  = (const float*)d_in[15];
    const float* w1     = (const float*)d_in[16];
    const float* b1     = (const float*)d_in[17];
    const float* w2     = (const float*)d_in[18];
    const float* b2     = (const float*)d_in[19];

    char* ws = (char*)d_ws;
    // layout (bytes):
    short* x_bf    = (short*)(ws + 0);            // 8,388,608 ; reused: vt, then h_bf
    short* vt      = (short*)(ws + 0);
    short* h_bf    = (short*)(ws + 0);
    short* w_qkvT  = (short*)(ws + 8388608);      // 6,291,456
    short* w_outT  = (short*)(ws + 14680064);     // 2,097,152
    short* w1T     = (short*)(ws + 16777216);     // 8,388,608
    short* w2T     = (short*)(ws + 25165824);     // 8,388,608
    short* qkv_bf  = (short*)(ws + 33554432);     // 25,165,824 (dead after rope+vtrans)
    short* pO0     = (short*)(ws + 33554432);     // 16,777,216
    float* pml     = (float*)(ws + 50331648);     // 1,048,576
    float* a_p0    = (float*)(ws + 33554432);     // 16,777,216 (after combine)
    short* q1      = (short*)(ws + 58720256);     // 4x 4,194,304 -> ends 75,497,472
    short* q2n     = (short*)(ws + 62914560);
    short* k1      = (short*)(ws + 67108864);
    short* k2n     = (short*)(ws + 71303168);
    float* a_p1    = (float*)(ws + 58720256);     // 16,777,216 (after attn)
    short* pO1     = (short*)(ws + 75497472);     // 16,777,216 -> ends 92,274,688
    short* arms    = (short*)(ws + 92274688);     // 8,388,608 -> ends 100,663,296
    short* ffh     = (short*)(ws + 33554432);     // 33,554,432 (after add_ln1) -> 67,108,864
    float* ff_p0   = (float*)(ws + 67108864);     // 16,777,216 -> 83,886,080
    float* ff_p1   = (float*)(ws + 83886080);     // 16,777,216 -> 100,663,296
    float* lam     = (float*)(ws + 100663296);

    // 1. lambda + fused prep (weight transposes + x convert)
    lam_kernel<<<1, 64, 0, stream>>>(lq1, lk1, lq2, lk2, lam);
    prep_kernel<<<16384, 256, 0, stream>>>(x, w_qkv, w_out, w1, w2,
                                           x_bf, w_qkvT, w_outT, w1T, w2T);

    // 2. qkv = x @ w_qkv -> bf16   (grid 24x32 = 768 blocks)
    gemm_bt<0, 1, 0><<<dim3(24, 32), 256, 0, stream>>>(x_bf, w_qkvT, nullptr,
                                                       qkv_bf, nullptr, NT_, 3072, 1024, 1024);

    // 3. rope + split + q2/k2 rmsnorm ; V transpose (x_bf dead now)
    rope_kernel<<<NT_, 256, 0, stream>>>(qkv_bf, sigmas, lnq_w, lnq_b, q1, q2n, k1, k2n);
    vtrans_kernel<<<dim3(S_ / 32, 4, 16), 256, 0, stream>>>(qkv_bf, vt);

    // 4. dual attention split-K partials + combine
    attn_part<<<1024, 256, 0, stream>>>(q1, q2n, k1, k2n, vt, pO0, pO1, pml);
    attn_combine<<<NT_, 256, 0, stream>>>(pO0, pO1, pml, lam, ln_w, ln_b, arms);

    // 5. a = arms @ w_out, split-K x2 -> f32 partials (grid 8x64 = 512 blocks)
    gemm_bt<0, 0, 1><<<dim3(8, 64), 256, 0, stream>>>(arms, w_outT, nullptr,
                                                      a_p0, a_p1, NT_, 1024, 1024, 512);

    // 6. h_bf = bf16(LN(a0 + a1 + x))
    add_ln1_kernel<<<NT_, 256, 0, stream>>>(a_p0, a_p1, x, ln1_w, ln1_b, h_bf);

    // 7. ffh = silu(h @ w1 + b1) -> bf16  (grid 32x32 = 1024 blocks)
    gemm_bt<2, 1, 0><<<dim3(32, 32), 256, 0, stream>>>(h_bf, w1T, b1,
                                                       ffh, nullptr, NT_, 4096, 1024, 1024);

    // 8. ff = ffh @ w2, split-K x2 -> f32 partials (grid 8x64 = 512 blocks)
    gemm_bt<0, 0, 1><<<dim3(8, 64), 256, 0, stream>>>(ffh, w2T, nullptr,
                                                      ff_p0, ff_p1, NT_, 1024, 4096, 2048);

    // 9. out = LN(ff0 + ff1 + b2 + h)
    add_ln2_kernel<<<NT_, 256, 0, stream>>>(ff_p0, ff_p1, b2, h_bf, ln2_w, ln2_b,
                                            (float*)d_out);
}

// Round 15
// 403.981 us; speedup vs baseline: 1.2752x; 1.2752x over previous
//
#include <hip/hip_runtime.h>
#include <math.h>
#include <stdint.h>

#define B_ 2
#define S_ 2048
#define D_ 1024
#define H_ 8
#define NT_ (B_*S_)   // 4096 tokens

static constexpr float LAMBDA_INIT = 0.47071301834358415f;
static constexpr float ONE_MINUS_LI = 1.0f - 0.47071301834358415f;

typedef __attribute__((ext_vector_type(8))) short bf16x8;
typedef __attribute__((ext_vector_type(4))) float f32x4;

__device__ __forceinline__ unsigned short f2bf(float x) {
    union { float f; unsigned int u; } v; v.f = x;
    unsigned int r = v.u + 0x7fffu + ((v.u >> 16) & 1u);
    return (unsigned short)(r >> 16);
}
__device__ __forceinline__ float bf2f(unsigned short b) {
    union { unsigned int u; float f; } v; v.u = ((unsigned int)b) << 16;
    return v.f;
}

#define GLD16(gp, lp) __builtin_amdgcn_global_load_lds( \
    (const __attribute__((address_space(1))) void*)(gp), \
    (__attribute__((address_space(3))) void*)(lp), 16, 0, 0)

// ---------------------------------------------------------------- lam scalar
__global__ void lam_kernel(const float* __restrict__ lq1, const float* __restrict__ lk1,
                           const float* __restrict__ lq2, const float* __restrict__ lk2,
                           float* __restrict__ lam_out) {
    int t = threadIdx.x;  // 64 threads
    float p1 = lq1[t] * lk1[t];
    float p2 = lq2[t] * lk2[t];
    for (int off = 32; off; off >>= 1) {
        p1 += __shfl_xor(p1, off);
        p2 += __shfl_xor(p2, off);
    }
    if (t == 0) lam_out[0] = expf(p1) - expf(p2) + LAMBDA_INIT;
}

// ------------------------------------------ fused prep: 4 weight transposes + x convert
__global__ __launch_bounds__(256) void prep_kernel(const float* __restrict__ x,
                                                   const float* __restrict__ w_qkv,
                                                   const float* __restrict__ w_out,
                                                   const float* __restrict__ w1,
                                                   const float* __restrict__ w2,
                                                   short* __restrict__ x_bf,
                                                   short* __restrict__ w_qkvT,
                                                   short* __restrict__ w_outT,
                                                   short* __restrict__ w1T,
                                                   short* __restrict__ w2T) {
    const int z = blockIdx.x;
    if (z >= 12288) {   // convert x
        const size_t i = ((size_t)(z - 12288) * 256 + threadIdx.x) * 4;
        float4 v = *(const float4*)(x + i);
        *(ushort4*)(x_bf + i) = make_ushort4(f2bf(v.x), f2bf(v.y), f2bf(v.z), f2bf(v.w));
        return;
    }
    const float* W; short* WT; int K, N, zz;
    if (z < 3072)      { W = w_qkv; WT = w_qkvT; K = 1024; N = 3072; zz = z; }
    else if (z < 4096) { W = w_out; WT = w_outT; K = 1024; N = 1024; zz = z - 3072; }
    else if (z < 8192) { W = w1;    WT = w1T;    K = 1024; N = 4096; zz = z - 4096; }
    else               { W = w2;    WT = w2T;    K = 4096; N = 1024; zz = z - 8192; }
    const int nx = N >> 5;
    const int bx = zz % nx, by = zz / nx;
    __shared__ float tile[32][33];
    const int t = threadIdx.x;
    const int k0 = by * 32, n0 = bx * 32;
    const int r = t >> 3, c0 = (t & 7) * 4;
    float4 v = *(const float4*)(W + (size_t)(k0 + r) * N + n0 + c0);
    tile[r][c0 + 0] = v.x; tile[r][c0 + 1] = v.y;
    tile[r][c0 + 2] = v.z; tile[r][c0 + 3] = v.w;
    __syncthreads();
    ushort4 o = make_ushort4(f2bf(tile[c0 + 0][r]), f2bf(tile[c0 + 1][r]),
                             f2bf(tile[c0 + 2][r]), f2bf(tile[c0 + 3][r]));
    *(ushort4*)(WT + (size_t)(n0 + r) * K + k0 + c0) = o;
}

// --------------------------------------------- V transpose: qkv V part -> vt[bh][e][s]
__global__ __launch_bounds__(256) void vtrans_kernel(const short* __restrict__ qkv_bf,
                                                     short* __restrict__ vt) {
    __shared__ short tile[32][34];
    const int s0 = blockIdx.x * 32, e0 = blockIdx.y * 32, bh = blockIdx.z;
    const int b = bh >> 3, h = bh & 7;
    const int t = threadIdx.x, r = t >> 3, c0 = (t & 7) * 4;
    ushort4 v = *(const ushort4*)(qkv_bf + (size_t)(b * S_ + s0 + r) * 3072 + 2048 + h * 128 + e0 + c0);
    tile[r][c0 + 0] = v.x; tile[r][c0 + 1] = v.y;
    tile[r][c0 + 2] = v.z; tile[r][c0 + 3] = v.w;
    __syncthreads();
    ushort4 o = make_ushort4((unsigned short)tile[c0 + 0][r], (unsigned short)tile[c0 + 1][r],
                             (unsigned short)tile[c0 + 2][r], (unsigned short)tile[c0 + 3][r]);
    *(ushort4*)(vt + ((size_t)bh * 128 + e0 + r) * S_ + s0 + c0) = o;
}

// ---------------------------------------------------------------- bf16 MFMA GEMM
// C = A @ BT^T. 128x128 tile, BK=32, 4 waves, 4x4 16x16 frags/wave.
// T4 pipeline: 3 LDS buffers, counted vmcnt(4), raw s_barrier. T2 source-side swizzle.
template <int EPI, int OUTBF, int SPLITK>
__global__ __launch_bounds__(256) void gemm_bt(const short* __restrict__ A,
                                               const short* __restrict__ BT,
                                               const float* __restrict__ bias,
                                               void* __restrict__ C0,
                                               void* __restrict__ C1,
                                               int M, int N, int Kfull, int Ksub) {
    __shared__ short As[3][128 * 32];
    __shared__ short Bs[3][128 * 32];
    const int t = threadIdx.x;
    const int w = t >> 6, l = t & 63;
    const int lr = l & 15, lg = l >> 4;

    // block remap: XCD-contiguous virtual index, split-K decode, shaped chunk
    const int GX = gridDim.x;
    const int nwg = GX * gridDim.y;
    int flat = blockIdx.y * GX + blockIdx.x;
    flat = (flat & 7) * (nwg >> 3) + (flat >> 3);      // XCD-contiguous
    int part = 0;
    if (SPLITK) { const int per = nwg >> 1; part = flat / per; flat = flat % per; }
    const int per_part = SPLITK ? (nwg >> 1) : nwg;
    const int GYp = per_part / GX;
    const int panel = flat / (8 * GYp);
    const int idx = flat % (8 * GYp);
    const int by = idx >> 3;
    const int bx = panel * 8 + (idx & 7);
    const int row0 = by * 128, col0 = bx * 128;
    const int wr = (w >> 1) * 64, wc = (w & 1) * 64;

    f32x4 acc[4][4];
#pragma unroll
    for (int i = 0; i < 4; ++i)
#pragma unroll
        for (int j = 0; j < 4; ++j) acc[i][j] = (f32x4){0.f, 0.f, 0.f, 0.f};

    // T2: pre-swizzled global k-slot (involution keyed on row bits 1-2 = (l>>3)&3)
    const int sg = ((l & 3) ^ ((l >> 3) & 3)) * 8;
    const short* Ag = A + (size_t)part * Ksub + (size_t)(row0 + w * 32 + (l >> 2)) * Kfull + sg;
    const short* Bg = BT + (size_t)part * Ksub + (size_t)(col0 + w * 32 + (l >> 2)) * Kfull + sg;

    const int nst = Ksub >> 5;

    auto stage = [&](int T, int Bf) {
#pragma unroll
        for (int j = 0; j < 2; ++j) {
            GLD16(Ag + (T << 5) + (size_t)j * 16 * Kfull, &As[Bf][(w * 2 + j) * 512]);
            GLD16(Bg + (T << 5) + (size_t)j * 16 * Kfull, &Bs[Bf][(w * 2 + j) * 512]);
        }
    };

    // prologue: tiles 0 and 1 in flight (8 loads/wave outstanding)
    stage(0, 0);
    stage(1, 1);

    // T2: swizzled read slot (per-lane constant)
    const int rslot = (lg ^ ((lr >> 1) & 3)) * 8;

    int cur = 0;
    for (int k = 0; k < nst; ++k) {
        if (k + 1 < nst) {
            asm volatile("s_waitcnt vmcnt(4)" ::: "memory");
        } else {
            asm volatile("s_waitcnt vmcnt(0)" ::: "memory");
        }
        __builtin_amdgcn_s_barrier();
        __builtin_amdgcn_sched_barrier(0);
        const int nk = k + 2;
        if (nk < nst) {
            int nb = cur + 2; if (nb >= 3) nb -= 3;
            stage(nk, nb);
        }
        bf16x8 af[4], bfr[4];
#pragma unroll
        for (int i = 0; i < 4; ++i)
            af[i] = *(const bf16x8*)(&As[cur][(wr + i * 16 + lr) * 32 + rslot]);
#pragma unroll
        for (int j = 0; j < 4; ++j)
            bfr[j] = *(const bf16x8*)(&Bs[cur][(wc + j * 16 + lr) * 32 + rslot]);
#pragma unroll
        for (int i = 0; i < 4; ++i)
#pragma unroll
            for (int j = 0; j < 4; ++j)
                acc[i][j] = __builtin_amdgcn_mfma_f32_16x16x32_bf16(af[i], bfr[j], acc[i][j], 0, 0, 0);
        __builtin_amdgcn_sched_barrier(0);
        asm volatile("s_waitcnt lgkmcnt(0)" ::: "memory");
        cur = (cur + 1 == 3) ? 0 : cur + 1;
    }

    void* Cout = (SPLITK && part) ? C1 : C0;
#pragma unroll
    for (int i = 0; i < 4; ++i) {
#pragma unroll
        for (int j = 0; j < 4; ++j) {
            const int col = col0 + wc + j * 16 + lr;
            float bcol = (EPI >= 1) ? bias[col] : 0.f;
#pragma unroll
            for (int r = 0; r < 4; ++r) {
                const int row = row0 + wr + i * 16 + lg * 4 + r;
                float v = acc[i][j][r];
                if (EPI >= 1) v += bcol;
                if (EPI == 2) v = v / (1.0f + expf(-v));
                if (OUTBF) ((short*)Cout)[(size_t)row * N + col] = (short)f2bf(v);
                else       ((float*)Cout)[(size_t)row * N + col] = v;
            }
        }
    }
}

// ------------------------------------------------- RoPE + split + q2/k2 RMSNorm (bf16 io)
__global__ __launch_bounds__(256) void rope_kernel(const short* __restrict__ qkv,
                                                   const float* __restrict__ sigmas,
                                                   const float* __restrict__ lnq_w,
                                                   const float* __restrict__ lnq_b,
                                                   short* __restrict__ q1, short* __restrict__ q2n,
                                                   short* __restrict__ k1, short* __restrict__ k2n) {
    const int tok = blockIdx.x;            // 0..4095
    const int b = tok >> 11, s = tok & 2047;
    const int t = threadIdx.x;
    const int hh = t >> 4;                 // 0..15 (head in 2H layout)
    const int d0 = (t & 15) * 4;

    const short* qrow = qkv + (size_t)tok * 3072 + hh * 64 + d0;
    ushort4 qv = *(const ushort4*)qrow;
    ushort4 kv = *(const ushort4*)(qrow + 1024);
    float q[4] = {bf2f(qv.x), bf2f(qv.y), bf2f(qv.z), bf2f(qv.w)};
    float k[4] = {bf2f(kv.x), bf2f(kv.y), bf2f(kv.z), bf2f(kv.w)};

    if (d0 < 32) {
#pragma unroll
        for (int pr = 0; pr < 2; ++pr) {
            const int i = d0 / 2 + pr;
            float freq = (float)s * powf(10000.0f, -(float)i / 16.0f);
            float sn, c;
            sincosf(freq, &sn, &c);
            float x0 = q[2 * pr], x1 = q[2 * pr + 1];
            q[2 * pr]     = x0 * c - x1 * sn;
            q[2 * pr + 1] = x1 * c + x0 * sn;
            x0 = k[2 * pr]; x1 = k[2 * pr + 1];
            k[2 * pr]     = x0 * c - x1 * sn;
            k[2 * pr + 1] = x1 * c + x0 * sn;
        }
    }

    const int h = hh >> 1, j = hh & 1;
    const size_t obase = ((size_t)(b * H_ + h) * S_ + s) * 64 + d0;
    if (j == 0) {
        *(ushort4*)&q1[obase] = make_ushort4(f2bf(q[0]), f2bf(q[1]), f2bf(q[2]), f2bf(q[3]));
        *(ushort4*)&k1[obase] = make_ushort4(f2bf(k[0]), f2bf(k[1]), f2bf(k[2]), f2bf(k[3]));
    } else {
        float ssq_q = 0.f, ssq_k = 0.f;
#pragma unroll
        for (int i = 0; i < 4; ++i) {
            const float sg = sigmas[b * 64 + d0 + i];
            q[i] += sg; k[i] += sg;
            ssq_q += q[i] * q[i];
            ssq_k += k[i] * k[i];
        }
        for (int off = 1; off < 16; off <<= 1) {
            ssq_q += __shfl_xor(ssq_q, off, 16);
            ssq_k += __shfl_xor(ssq_k, off, 16);
        }
        const float rq = rsqrtf(ssq_q / 64.0f + 1e-8f);
        const float rk = rsqrtf(ssq_k / 64.0f + 1e-8f);
        float oq[4], ok[4];
#pragma unroll
        for (int i = 0; i < 4; ++i) {
            const float w = lnq_w[d0 + i], bb = lnq_b[d0 + i];
            oq[i] = q[i] * rq * w + bb;
            ok[i] = k[i] * rk * w + bb;
        }
        *(ushort4*)&q2n[obase] = make_ushort4(f2bf(oq[0]), f2bf(oq[1]), f2bf(oq[2]), f2bf(oq[3]));
        *(ushort4*)&k2n[obase] = make_ushort4(f2bf(ok[0]), f2bf(ok[1]), f2bf(ok[2]), f2bf(ok[3]));
    }
}

// ------------------------------------------------- softmax update (per wave, one branch)
// T13 defer-rescale: skip O-rescale when running max grows <= 8 (P bounded by e^8).
__device__ __forceinline__ void sm_update(f32x4 (&s)[4], float (&m)[4], float (&lsum)[4],
                                          f32x4 (&o)[8], short* __restrict__ Pw,
                                          const bool diag, const int qr0, const int k0,
                                          const int lr, const int lg) {
    float nm[4];
#pragma unroll
    for (int r = 0; r < 4; ++r) nm[r] = m[r];
#pragma unroll
    for (int ks = 0; ks < 4; ++ks) {
#pragma unroll
        for (int r = 0; r < 4; ++r) {
            float v = s[ks][r];
            if (diag && (k0 + ks * 16 + lr > qr0 + r)) v = -INFINITY;
            else v *= 0.125f;
            s[ks][r] = v;
            nm[r] = fmaxf(nm[r], v);
        }
    }
#pragma unroll
    for (int r = 0; r < 4; ++r) {
        nm[r] = fmaxf(nm[r], __shfl_xor(nm[r], 1));
        nm[r] = fmaxf(nm[r], __shfl_xor(nm[r], 2));
        nm[r] = fmaxf(nm[r], __shfl_xor(nm[r], 4));
        nm[r] = fmaxf(nm[r], __shfl_xor(nm[r], 8));
    }
    bool grow = false;
#pragma unroll
    for (int r = 0; r < 4; ++r) grow = grow || (nm[r] > m[r] + 8.0f);
    if (__any(grow)) {
        float al[4];
#pragma unroll
        for (int r = 0; r < 4; ++r) {
            al[r] = __expf(m[r] - nm[r]);
            m[r] = nm[r];
            lsum[r] *= al[r];
        }
#pragma unroll
        for (int es = 0; es < 8; ++es) {
#pragma unroll
            for (int r = 0; r < 4; ++r) o[es][r] *= al[r];
        }
    }
    float rs[4] = {0.f, 0.f, 0.f, 0.f};
#pragma unroll
    for (int ks = 0; ks < 4; ++ks) {
#pragma unroll
        for (int r = 0; r < 4; ++r) {
            float p = __expf(s[ks][r] - m[r]);
            rs[r] += p;
            Pw[(lg * 4 + r) * 72 + ks * 16 + lr] = (short)f2bf(p);
        }
    }
#pragma unroll
    for (int r = 0; r < 4; ++r) {
        rs[r] += __shfl_xor(rs[r], 1);
        rs[r] += __shfl_xor(rs[r], 2);
        rs[r] += __shfl_xor(rs[r], 4);
        rs[r] += __shfl_xor(rs[r], 8);
        lsum[r] += rs[r];
    }
}

// ------------------------------------------------- dual attention, split-K partials
// 1024 blocks x 256 threads (4 waves). QBLK=64, KVBLK=64. XCD-swizzled (2 bh/XCD).
// V^T read DIRECTLY from global (L2-resident ~1MB/XCD). LDS 28KB.
// launch_bounds(256,3): 170-reg budget — (256,4)'s 128-reg budget spilled to
// scratch (round 14: VGPR 64, 317MB phantom writes). Occupancy is then set by
// actual VGPR use (~100 -> up to 5 waves/SIMD) and LDS (5 blocks), not forced.
__global__ __launch_bounds__(256, 3) void attn_part(const short* __restrict__ q1g,
                                                    const short* __restrict__ q2g,
                                                    const short* __restrict__ k1g,
                                                    const short* __restrict__ k2g,
                                                    const short* __restrict__ vt,
                                                    short* __restrict__ pO0,
                                                    short* __restrict__ pO1,
                                                    float* __restrict__ pml) {
    __shared__ short Ks1[64 * 72];
    __shared__ short Ks2[64 * 72];
    __shared__ short Ps[4][16 * 72];   // per-wave P (reused across branches)

    const int i = blockIdx.x;            // 0..1023
    const int xcd = i & 7;
    const int slot = i >> 3;             // 0..127
    const int a = slot >> 6;             // bh within xcd
    const int j = slot & 63;
    const int qt = 31 - (j >> 1);        // LPT: big first
    const int part = j & 1;
    const int bh = xcd * 2 + a;
    const int q0 = qt * 64;
    const int t = threadIdx.x, w = t >> 6, l = t & 63;
    const int lr = l & 15, lg = l >> 4;

    const size_t kbase = (size_t)bh * S_ * 64;
    const size_t vbase = (size_t)bh * 128 * S_;

    // Q fragments (wave w owns rows q0 + w*16 .. +15)
    bf16x8 qa1[2], qa2[2];
    {
        const size_t rb = kbase + (size_t)(q0 + w * 16 + lr) * 64;
#pragma unroll
        for (int dh = 0; dh < 2; ++dh) {
            qa1[dh] = *(const bf16x8*)(q1g + rb + dh * 32 + lg * 8);
            qa2[dh] = *(const bf16x8*)(q2g + rb + dh * 32 + lg * 8);
        }
    }

    const int nkt = qt + 1, mid = (nkt + 1) >> 1;
    const int kt0 = part ? mid : 0, kt1 = part ? nkt : mid;

    float m1[4], m2[4], l1[4], l2[4];
#pragma unroll
    for (int r = 0; r < 4; ++r) { m1[r] = -1e30f; m2[r] = -1e30f; l1[r] = 0.f; l2[r] = 0.f; }
    f32x4 o1[8], o2[8];
#pragma unroll
    for (int es = 0; es < 8; ++es) { o1[es] = (f32x4){0.f,0.f,0.f,0.f}; o2[es] = (f32x4){0.f,0.f,0.f,0.f}; }

    short* Pw = &Ps[w][0];
    const int qr0 = q0 + w * 16 + lg * 4;
    const int wrow_lo = q0 + w * 16;

    const int sr = t >> 2, sc = (t & 3) * 16;   // K staging: 64 rows x 16 elems

    for (int kt = kt0; kt < kt1; ++kt) {
        const int k0 = kt * 64;
        __syncthreads();   // prior tile reads done
        // stage K1,K2 [64][72] (vectorized 16B, coalesced)
        {
            const size_t g = kbase + (size_t)(k0 + sr) * 64 + sc;
            *(bf16x8*)(Ks1 + sr * 72 + sc)     = *(const bf16x8*)(k1g + g);
            *(bf16x8*)(Ks1 + sr * 72 + sc + 8) = *(const bf16x8*)(k1g + g + 8);
            *(bf16x8*)(Ks2 + sr * 72 + sc)     = *(const bf16x8*)(k2g + g);
            *(bf16x8*)(Ks2 + sr * 72 + sc + 8) = *(const bf16x8*)(k2g + g + 8);
        }
        __syncthreads();

        const bool diag = (k0 + 63 > wrow_lo);
        const short* vtile = vt + vbase + k0;

        // ---- branch 1
        {
            f32x4 s[4];
#pragma unroll
            for (int ks = 0; ks < 4; ++ks) s[ks] = (f32x4){0.f,0.f,0.f,0.f};
            __builtin_amdgcn_s_setprio(1);
#pragma unroll
            for (int ks = 0; ks < 4; ++ks)
#pragma unroll
                for (int dh = 0; dh < 2; ++dh) {
                    bf16x8 kf = *(const bf16x8*)(Ks1 + (ks * 16 + lr) * 72 + dh * 32 + lg * 8);
                    s[ks] = __builtin_amdgcn_mfma_f32_16x16x32_bf16(qa1[dh], kf, s[ks], 0, 0, 0);
                }
            __builtin_amdgcn_s_setprio(0);
            sm_update(s, m1, l1, o1, Pw, diag, qr0, k0, lr, lg);
            __builtin_amdgcn_s_setprio(1);
#pragma unroll
            for (int kb = 0; kb < 2; ++kb) {
                bf16x8 pf = *(const bf16x8*)(Pw + lr * 72 + kb * 32 + lg * 8);
#pragma unroll
                for (int es = 0; es < 8; ++es) {
                    bf16x8 vf = *(const bf16x8*)(vtile + (size_t)(es * 16 + lr) * S_ + kb * 32 + lg * 8);
                    o1[es] = __builtin_amdgcn_mfma_f32_16x16x32_bf16(pf, vf, o1[es], 0, 0, 0);
                }
            }
            __builtin_amdgcn_s_setprio(0);
        }
        // ---- branch 2
        {
            f32x4 s[4];
#pragma unroll
            for (int ks = 0; ks < 4; ++ks) s[ks] = (f32x4){0.f,0.f,0.f,0.f};
            __builtin_amdgcn_s_setprio(1);
#pragma unroll
            for (int ks = 0; ks < 4; ++ks)
#pragma unroll
                for (int dh = 0; dh < 2; ++dh) {
                    bf16x8 kf = *(const bf16x8*)(Ks2 + (ks * 16 + lr) * 72 + dh * 32 + lg * 8);
                    s[ks] = __builtin_amdgcn_mfma_f32_16x16x32_bf16(qa2[dh], kf, s[ks], 0, 0, 0);
                }
            __builtin_amdgcn_s_setprio(0);
            sm_update(s, m2, l2, o2, Pw, diag, qr0, k0, lr, lg);
            __builtin_amdgcn_s_setprio(1);
#pragma unroll
            for (int kb = 0; kb < 2; ++kb) {
                bf16x8 pf = *(const bf16x8*)(Pw + lr * 72 + kb * 32 + lg * 8);
#pragma unroll
                for (int es = 0; es < 8; ++es) {
                    bf16x8 vf = *(const bf16x8*)(vtile + (size_t)(es * 16 + lr) * S_ + kb * 32 + lg * 8);
                    o2[es] = __builtin_amdgcn_mfma_f32_16x16x32_bf16(pf, vf, o2[es], 0, 0, 0);
                }
            }
            __builtin_amdgcn_s_setprio(0);
        }
    }

    // store partials: packed 2xbf16 uints, wave-fragment layout, fully coalesced.
    {
        uint32_t* pO = (uint32_t*)(part ? pO1 : pO0);
        const size_t wb = (((size_t)bh * 32 + qt) * 4 + w) * 2048;
#pragma unroll
        for (int r = 0; r < 4; ++r) {
#pragma unroll
            for (int u = 0; u < 4; ++u) {
                uint32_t v1 = (uint32_t)f2bf(o1[2 * u][r]) | ((uint32_t)f2bf(o1[2 * u + 1][r]) << 16);
                pO[wb + (size_t)((r * 2 + 0) * 4 + u) * 64 + l] = v1;
                uint32_t v2 = (uint32_t)f2bf(o2[2 * u][r]) | ((uint32_t)f2bf(o2[2 * u + 1][r]) << 16);
                pO[wb + (size_t)((r * 2 + 1) * 4 + u) * 64 + l] = v2;
            }
        }
    }
    if (lr == 0) {
#pragma unroll
        for (int r = 0; r < 4; ++r) {
            const int q = q0 + w * 16 + lg * 4 + r;
            float4 v = make_float4(m1[r], l1[r], m2[r], l2[r]);
            *(float4*)&pml[(((size_t)part * 16 + bh) * S_ + q) * 4] = v;
        }
    }
}

// ------------------------------------------------- combine partials + diff + RMSNorm
__global__ __launch_bounds__(256) void attn_combine(const short* __restrict__ pO0,
                                                    const short* __restrict__ pO1,
                                                    const float* __restrict__ pml,
                                                    const float* __restrict__ lamp,
                                                    const float* __restrict__ ln_w,
                                                    const float* __restrict__ ln_b,
                                                    short* __restrict__ arms) {
    const int tok = blockIdx.x;           // 0..4095
    const int b = tok >> 11, q = tok & 2047;
    const int t = threadIdx.x;
    const int h = t >> 5, ln32 = t & 31, e0 = ln32 * 4;
    const int bh = b * H_ + h;
    const float lam = lamp[0];

    float4 mla = *(const float4*)&pml[(((size_t)0 * 16 + bh) * S_ + q) * 4];
    float4 mlb = *(const float4*)&pml[(((size_t)1 * 16 + bh) * S_ + q) * 4];

    const float m1 = fmaxf(mla.x, mlb.x);
    const float aa1 = __expf(mla.x - m1), ab1 = __expf(mlb.x - m1);
    const float il1 = 1.0f / (aa1 * mla.y + ab1 * mlb.y);
    const float m2 = fmaxf(mla.z, mlb.z);
    const float aa2 = __expf(mla.z - m2), ab2 = __expf(mlb.z - m2);
    const float il2 = 1.0f / (aa2 * mla.w + ab2 * mlb.w);

    // decode packed wave-fragment layout (QBLK=64: qt=q>>6, w=(q>>4)&3)
    const int qt = q >> 6, w = (q >> 4) & 3, lg = (q >> 2) & 3, r = q & 3;
    const int es = ln32 >> 2, u = es >> 1, half = es & 1;
    const int lane0 = lg * 16 + (ln32 & 3) * 4;
    const size_t wb = (((size_t)bh * 32 + qt) * 4 + w) * 2048;
    const uint32_t* P0 = (const uint32_t*)pO0;
    const uint32_t* P1 = (const uint32_t*)pO1;
    const uint4 a1  = *(const uint4*)&P0[wb + (size_t)((r * 2 + 0) * 4 + u) * 64 + lane0];
    const uint4 b1v = *(const uint4*)&P1[wb + (size_t)((r * 2 + 0) * 4 + u) * 64 + lane0];
    const uint4 a2  = *(const uint4*)&P0[wb + (size_t)((r * 2 + 1) * 4 + u) * 64 + lane0];
    const uint4 b2v = *(const uint4*)&P1[wb + (size_t)((r * 2 + 1) * 4 + u) * 64 + lane0];
    const int sh = 16 * half;

    float comb[4]; float ssq = 0.f;
    {
        const uint32_t aw1[4] = {a1.x, a1.y, a1.z, a1.w};
        const uint32_t bw1[4] = {b1v.x, b1v.y, b1v.z, b1v.w};
        const uint32_t aw2[4] = {a2.x, a2.y, a2.z, a2.w};
        const uint32_t bw2[4] = {b2v.x, b2v.y, b2v.z, b2v.w};
#pragma unroll
        for (int i = 0; i < 4; ++i) {
            const float O1 = (aa1 * bf2f((unsigned short)(aw1[i] >> sh)) +
                              ab1 * bf2f((unsigned short)(bw1[i] >> sh))) * il1;
            const float O2 = (aa2 * bf2f((unsigned short)(aw2[i] >> sh)) +
                              ab2 * bf2f((unsigned short)(bw2[i] >> sh))) * il2;
            const float c = O1 - lam * O2;
            comb[i] = c; ssq += c * c;
        }
    }
    for (int off = 1; off < 32; off <<= 1) ssq += __shfl_xor(ssq, off, 32);
    const float rms = rsqrtf(ssq / 128.0f + 1e-8f);

    ushort4 o;
    unsigned short* op = (unsigned short*)&o;
#pragma unroll
    for (int i = 0; i < 4; ++i) {
        const int e = e0 + i;
        op[i] = f2bf((comb[i] * rms * ln_w[e] + ln_b[e]) * ONE_MINUS_LI);
    }
    *(ushort4*)&arms[(size_t)tok * 1024 + h * 128 + e0] = o;
}

// -------------------------- add_ln1: h_bf = bf16( LN(a0 + a1 + x) )
__global__ __launch_bounds__(256) void add_ln1_kernel(const float* __restrict__ A0,
                                                      const float* __restrict__ A1,
                                                      const float* __restrict__ X,
                                                      const float* __restrict__ w,
                                                      const float* __restrict__ bvec,
                                                      short* __restrict__ out_bf) {
    const int row = blockIdx.x;
    const int t = threadIdx.x;
    __shared__ float red[4];

    float4 a0 = *(const float4*)&A0[(size_t)row * 1024 + t * 4];
    float4 a1 = *(const float4*)&A1[(size_t)row * 1024 + t * 4];
    float4 xv = *(const float4*)&X[(size_t)row * 1024 + t * 4];
    float v[4] = {a0.x + a1.x + xv.x, a0.y + a1.y + xv.y,
                  a0.z + a1.z + xv.z, a0.w + a1.w + xv.w};

    float s = v[0] + v[1] + v[2] + v[3];
    for (int off = 1; off < 64; off <<= 1) s += __shfl_xor(s, off);
    if ((t & 63) == 0) red[t >> 6] = s;
    __syncthreads();
    const float mean = (red[0] + red[1] + red[2] + red[3]) * (1.0f / 1024.0f);

    float sq = 0.f;
#pragma unroll
    for (int i = 0; i < 4; ++i) { const float d = v[i] - mean; sq += d * d; }
    __syncthreads();
    for (int off = 1; off < 64; off <<= 1) sq += __shfl_xor(sq, off);
    if ((t & 63) == 0) red[t >> 6] = sq;
    __syncthreads();
    const float var = (red[0] + red[1] + red[2] + red[3]) * (1.0f / 1024.0f);
    const float rstd = rsqrtf(var + 1e-5f);

    ushort4 o;
    unsigned short* op = (unsigned short*)&o;
#pragma unroll
    for (int i = 0; i < 4; ++i)
        op[i] = f2bf((v[i] - mean) * rstd * w[t * 4 + i] + bvec[t * 4 + i]);
    *(ushort4*)&out_bf[(size_t)row * 1024 + t * 4] = o;
}

// -------------------------- add_ln2: out = LN(f0 + f1 + bias + h_bf)  (f32 out)
__global__ __launch_bounds__(256) void add_ln2_kernel(const float* __restrict__ F0,
                                                      const float* __restrict__ F1,
                                                      const float* __restrict__ bias,
                                                      const short* __restrict__ Hbf,
                                                      const float* __restrict__ w,
                                                      const float* __restrict__ bvec,
                                                      float* __restrict__ out) {
    const int row = blockIdx.x;
    const int t = threadIdx.x;
    __shared__ float red[4];

    float4 f0 = *(const float4*)&F0[(size_t)row * 1024 + t * 4];
    float4 f1 = *(const float4*)&F1[(size_t)row * 1024 + t * 4];
    float4 bv = *(const float4*)&bias[t * 4];
    ushort4 hv = *(const ushort4*)&Hbf[(size_t)row * 1024 + t * 4];
    float v[4] = {f0.x + f1.x + bv.x + bf2f(hv.x), f0.y + f1.y + bv.y + bf2f(hv.y),
                  f0.z + f1.z + bv.z + bf2f(hv.z), f0.w + f1.w + bv.w + bf2f(hv.w)};

    float s = v[0] + v[1] + v[2] + v[3];
    for (int off = 1; off < 64; off <<= 1) s += __shfl_xor(s, off);
    if ((t & 63) == 0) red[t >> 6] = s;
    __syncthreads();
    const float mean = (red[0] + red[1] + red[2] + red[3]) * (1.0f / 1024.0f);

    float sq = 0.f;
#pragma unroll
    for (int i = 0; i < 4; ++i) { const float d = v[i] - mean; sq += d * d; }
    __syncthreads();
    for (int off = 1; off < 64; off <<= 1) sq += __shfl_xor(sq, off);
    if ((t & 63) == 0) red[t >> 6] = sq;
    __syncthreads();
    const float var = (red[0] + red[1] + red[2] + red[3]) * (1.0f / 1024.0f);
    const float rstd = rsqrtf(var + 1e-5f);

    float o[4];
#pragma unroll
    for (int i = 0; i < 4; ++i)
        o[i] = (v[i] - mean) * rstd * w[t * 4 + i] + bvec[t * 4 + i];
    *(float4*)&out[(size_t)row * 1024 + t * 4] = make_float4(o[0], o[1], o[2], o[3]);
}

// ---------------------------------------------------------------- launch
extern "C" void kernel_launch(void* const* d_in, const int* in_sizes, int n_in,
                              void* d_out, int out_size, void* d_ws, size_t ws_size,
                              hipStream_t stream) {
    const float* x      = (const float*)d_in[0];
    const float* sigmas = (const float*)d_in[1];
    const float* w_qkv  = (const float*)d_in[2];
    const float* w_out  = (const float*)d_in[3];
    const float* lq1    = (const float*)d_in[4];
    const float* lk1    = (const float*)d_in[5];
    const float* lq2    = (const float*)d_in[6];
    const float* lk2    = (const float*)d_in[7];
    const float* ln_w   = (const float*)d_in[8];
    const float* ln_b   = (const float*)d_in[9];
    const float* lnq_w  = (const float*)d_in[10];
    const float* lnq_b  = (const float*)d_in[11];
    const float* ln1_w  = (const float*)d_in[12];
    const float* ln1_b  = (const float*)d_in[13];
    const float* ln2_w  = (const float*)d_in[14];
    const float* ln2_b  = (const float*)d_in[15];
    const float* w1     = (const float*)d_in[16];
    const float* b1     = (const float*)d_in[17];
    const float* w2     = (const float*)d_in[18];
    const float* b2     = (const float*)d_in[19];

    char* ws = (char*)d_ws;
    // layout (bytes):
    short* x_bf    = (short*)(ws + 0);            // 8,388,608 ; reused: vt, then h_bf
    short* vt      = (short*)(ws + 0);
    short* h_bf    = (short*)(ws + 0);
    short* w_qkvT  = (short*)(ws + 8388608);      // 6,291,456
    short* w_outT  = (short*)(ws + 14680064);     // 2,097,152
    short* w1T     = (short*)(ws + 16777216);     // 8,388,608
    short* w2T     = (short*)(ws + 25165824);     // 8,388,608
    short* qkv_bf  = (short*)(ws + 33554432);     // 25,165,824 (dead after rope+vtrans)
    short* pO0     = (short*)(ws + 33554432);     // 16,777,216
    float* pml     = (float*)(ws + 50331648);     // 1,048,576
    float* a_p0    = (float*)(ws + 33554432);     // 16,777,216 (after combine)
    short* q1      = (short*)(ws + 58720256);     // 4x 4,194,304 -> ends 75,497,472
    short* q2n     = (short*)(ws + 62914560);
    short* k1      = (short*)(ws + 67108864);
    short* k2n     = (short*)(ws + 71303168);
    float* a_p1    = (float*)(ws + 58720256);     // 16,777,216 (after attn)
    short* pO1     = (short*)(ws + 75497472);     // 16,777,216 -> ends 92,274,688
    short* arms    = (short*)(ws + 92274688);     // 8,388,608 -> ends 100,663,296
    short* ffh     = (short*)(ws + 33554432);     // 33,554,432 (after add_ln1) -> 67,108,864
    float* ff_p0   = (float*)(ws + 67108864);     // 16,777,216 -> 83,886,080
    float* ff_p1   = (float*)(ws + 83886080);     // 16,777,216 -> 100,663,296
    float* lam     = (float*)(ws + 100663296);

    // 1. lambda + fused prep (weight transposes + x convert)
    lam_kernel<<<1, 64, 0, stream>>>(lq1, lk1, lq2, lk2, lam);
    prep_kernel<<<16384, 256, 0, stream>>>(x, w_qkv, w_out, w1, w2,
                                           x_bf, w_qkvT, w_outT, w1T, w2T);

    // 2. qkv = x @ w_qkv -> bf16   (grid 24x32 = 768 blocks)
    gemm_bt<0, 1, 0><<<dim3(24, 32), 256, 0, stream>>>(x_bf, w_qkvT, nullptr,
                                                       qkv_bf, nullptr, NT_, 3072, 1024, 1024);

    // 3. rope + split + q2/k2 rmsnorm ; V transpose (x_bf dead now)
    rope_kernel<<<NT_, 256, 0, stream>>>(qkv_bf, sigmas, lnq_w, lnq_b, q1, q2n, k1, k2n);
    vtrans_kernel<<<dim3(S_ / 32, 4, 16), 256, 0, stream>>>(qkv_bf, vt);

    // 4. dual attention split-K partials + combine
    attn_part<<<1024, 256, 0, stream>>>(q1, q2n, k1, k2n, vt, pO0, pO1, pml);
    attn_combine<<<NT_, 256, 0, stream>>>(pO0, pO1, pml, lam, ln_w, ln_b, arms);

    // 5. a = arms @ w_out, split-K x2 -> f32 partials (grid 8x64 = 512 blocks)
    gemm_bt<0, 0, 1><<<dim3(8, 64), 256, 0, stream>>>(arms, w_outT, nullptr,
                                                      a_p0, a_p1, NT_, 1024, 1024, 512);

    // 6. h_bf = bf16(LN(a0 + a1 + x))
    add_ln1_kernel<<<NT_, 256, 0, stream>>>(a_p0, a_p1, x, ln1_w, ln1_b, h_bf);

    // 7. ffh = silu(h @ w1 + b1) -> bf16  (grid 32x32 = 1024 blocks)
    gemm_bt<2, 1, 0><<<dim3(32, 32), 256, 0, stream>>>(h_bf, w1T, b1,
                                                       ffh, nullptr, NT_, 4096, 1024, 1024);

    // 8. ff = ffh @ w2, split-K x2 -> f32 partials (grid 8x64 = 512 blocks)
    gemm_bt<0, 0, 1><<<dim3(8, 64), 256, 0, stream>>>(ffh, w2T, nullptr,
                                                      ff_p0, ff_p1, NT_, 1024, 4096, 2048);

    // 9. out = LN(ff0 + ff1 + b2 + h)
    add_ln2_kernel<<<NT_, 256, 0, stream>>>(ff_p0, ff_p1, b2, h_bf, ln2_w, ln2_b,
                                            (float*)d_out);
}

// Round 16
// 314.881 us; speedup vs baseline: 1.6360x; 1.2830x over previous
//
#include <hip/hip_runtime.h>
#include <math.h>
#include <stdint.h>

#define B_ 2
#define S_ 2048
#define D_ 1024
#define H_ 8
#define NT_ (B_*S_)   // 4096 tokens

static constexpr float LAMBDA_INIT = 0.47071301834358415f;
static constexpr float ONE_MINUS_LI = 1.0f - 0.47071301834358415f;

typedef __attribute__((ext_vector_type(8))) short bf16x8;
typedef __attribute__((ext_vector_type(4))) float f32x4;

__device__ __forceinline__ unsigned short f2bf(float x) {
    union { float f; unsigned int u; } v; v.f = x;
    unsigned int r = v.u + 0x7fffu + ((v.u >> 16) & 1u);
    return (unsigned short)(r >> 16);
}
__device__ __forceinline__ float bf2f(unsigned short b) {
    union { unsigned int u; float f; } v; v.u = ((unsigned int)b) << 16;
    return v.f;
}

#define GLD16(gp, lp) __builtin_amdgcn_global_load_lds( \
    (const __attribute__((address_space(1))) void*)(gp), \
    (__attribute__((address_space(3))) void*)(lp), 16, 0, 0)

// ---------------------------------------------------------------- lam scalar
__global__ void lam_kernel(const float* __restrict__ lq1, const float* __restrict__ lk1,
                           const float* __restrict__ lq2, const float* __restrict__ lk2,
                           float* __restrict__ lam_out) {
    int t = threadIdx.x;  // 64 threads
    float p1 = lq1[t] * lk1[t];
    float p2 = lq2[t] * lk2[t];
    for (int off = 32; off; off >>= 1) {
        p1 += __shfl_xor(p1, off);
        p2 += __shfl_xor(p2, off);
    }
    if (t == 0) lam_out[0] = expf(p1) - expf(p2) + LAMBDA_INIT;
}

// ------------------------------------------ fused prep: 4 weight transposes + x convert
__global__ __launch_bounds__(256) void prep_kernel(const float* __restrict__ x,
                                                   const float* __restrict__ w_qkv,
                                                   const float* __restrict__ w_out,
                                                   const float* __restrict__ w1,
                                                   const float* __restrict__ w2,
                                                   short* __restrict__ x_bf,
                                                   short* __restrict__ w_qkvT,
                                                   short* __restrict__ w_outT,
                                                   short* __restrict__ w1T,
                                                   short* __restrict__ w2T) {
    const int z = blockIdx.x;
    if (z >= 12288) {   // convert x
        const size_t i = ((size_t)(z - 12288) * 256 + threadIdx.x) * 4;
        float4 v = *(const float4*)(x + i);
        *(ushort4*)(x_bf + i) = make_ushort4(f2bf(v.x), f2bf(v.y), f2bf(v.z), f2bf(v.w));
        return;
    }
    const float* W; short* WT; int K, N, zz;
    if (z < 3072)      { W = w_qkv; WT = w_qkvT; K = 1024; N = 3072; zz = z; }
    else if (z < 4096) { W = w_out; WT = w_outT; K = 1024; N = 1024; zz = z - 3072; }
    else if (z < 8192) { W = w1;    WT = w1T;    K = 1024; N = 4096; zz = z - 4096; }
    else               { W = w2;    WT = w2T;    K = 4096; N = 1024; zz = z - 8192; }
    const int nx = N >> 5;
    const int bx = zz % nx, by = zz / nx;
    __shared__ float tile[32][33];
    const int t = threadIdx.x;
    const int k0 = by * 32, n0 = bx * 32;
    const int r = t >> 3, c0 = (t & 7) * 4;
    float4 v = *(const float4*)(W + (size_t)(k0 + r) * N + n0 + c0);
    tile[r][c0 + 0] = v.x; tile[r][c0 + 1] = v.y;
    tile[r][c0 + 2] = v.z; tile[r][c0 + 3] = v.w;
    __syncthreads();
    ushort4 o = make_ushort4(f2bf(tile[c0 + 0][r]), f2bf(tile[c0 + 1][r]),
                             f2bf(tile[c0 + 2][r]), f2bf(tile[c0 + 3][r]));
    *(ushort4*)(WT + (size_t)(n0 + r) * K + k0 + c0) = o;
}

// --------------------------------------------- V transpose: qkv V part -> vt[bh][e][s]
__global__ __launch_bounds__(256) void vtrans_kernel(const short* __restrict__ qkv_bf,
                                                     short* __restrict__ vt) {
    __shared__ short tile[32][34];
    const int s0 = blockIdx.x * 32, e0 = blockIdx.y * 32, bh = blockIdx.z;
    const int b = bh >> 3, h = bh & 7;
    const int t = threadIdx.x, r = t >> 3, c0 = (t & 7) * 4;
    ushort4 v = *(const ushort4*)(qkv_bf + (size_t)(b * S_ + s0 + r) * 3072 + 2048 + h * 128 + e0 + c0);
    tile[r][c0 + 0] = v.x; tile[r][c0 + 1] = v.y;
    tile[r][c0 + 2] = v.z; tile[r][c0 + 3] = v.w;
    __syncthreads();
    ushort4 o = make_ushort4((unsigned short)tile[c0 + 0][r], (unsigned short)tile[c0 + 1][r],
                             (unsigned short)tile[c0 + 2][r], (unsigned short)tile[c0 + 3][r]);
    *(ushort4*)(vt + ((size_t)bh * 128 + e0 + r) * S_ + s0 + c0) = o;
}

// ---------------------------------------------------------------- 128x128 bf16 GEMM
// (split-K / small-N path). T4 pipeline: 3 LDS buffers, counted vmcnt(4), raw
// s_barrier. T2 source-side swizzle.
template <int EPI, int OUTBF, int SPLITK>
__global__ __launch_bounds__(256) void gemm_bt(const short* __restrict__ A,
                                               const short* __restrict__ BT,
                                               const float* __restrict__ bias,
                                               void* __restrict__ C0,
                                               void* __restrict__ C1,
                                               int M, int N, int Kfull, int Ksub) {
    __shared__ short As[3][128 * 32];
    __shared__ short Bs[3][128 * 32];
    const int t = threadIdx.x;
    const int w = t >> 6, l = t & 63;
    const int lr = l & 15, lg = l >> 4;

    const int GX = gridDim.x;
    const int nwg = GX * gridDim.y;
    int flat = blockIdx.y * GX + blockIdx.x;
    flat = (flat & 7) * (nwg >> 3) + (flat >> 3);      // XCD-contiguous
    int part = 0;
    if (SPLITK) { const int per = nwg >> 1; part = flat / per; flat = flat % per; }
    const int per_part = SPLITK ? (nwg >> 1) : nwg;
    const int GYp = per_part / GX;
    const int panel = flat / (8 * GYp);
    const int idx = flat % (8 * GYp);
    const int by = idx >> 3;
    const int bx = panel * 8 + (idx & 7);
    const int row0 = by * 128, col0 = bx * 128;
    const int wr = (w >> 1) * 64, wc = (w & 1) * 64;

    f32x4 acc[4][4];
#pragma unroll
    for (int i = 0; i < 4; ++i)
#pragma unroll
        for (int j = 0; j < 4; ++j) acc[i][j] = (f32x4){0.f, 0.f, 0.f, 0.f};

    const int sg = ((l & 3) ^ ((l >> 3) & 3)) * 8;
    const short* Ag = A + (size_t)part * Ksub + (size_t)(row0 + w * 32 + (l >> 2)) * Kfull + sg;
    const short* Bg = BT + (size_t)part * Ksub + (size_t)(col0 + w * 32 + (l >> 2)) * Kfull + sg;

    const int nst = Ksub >> 5;

    auto stage = [&](int T, int Bf) {
#pragma unroll
        for (int j = 0; j < 2; ++j) {
            GLD16(Ag + (T << 5) + (size_t)j * 16 * Kfull, &As[Bf][(w * 2 + j) * 512]);
            GLD16(Bg + (T << 5) + (size_t)j * 16 * Kfull, &Bs[Bf][(w * 2 + j) * 512]);
        }
    };

    stage(0, 0);
    stage(1, 1);

    const int rslot = (lg ^ ((lr >> 1) & 3)) * 8;

    int cur = 0;
    for (int k = 0; k < nst; ++k) {
        if (k + 1 < nst) {
            asm volatile("s_waitcnt vmcnt(4)" ::: "memory");
        } else {
            asm volatile("s_waitcnt vmcnt(0)" ::: "memory");
        }
        __builtin_amdgcn_s_barrier();
        __builtin_amdgcn_sched_barrier(0);
        const int nk = k + 2;
        if (nk < nst) {
            int nb = cur + 2; if (nb >= 3) nb -= 3;
            stage(nk, nb);
        }
        bf16x8 af[4], bfr[4];
#pragma unroll
        for (int i = 0; i < 4; ++i)
            af[i] = *(const bf16x8*)(&As[cur][(wr + i * 16 + lr) * 32 + rslot]);
#pragma unroll
        for (int j = 0; j < 4; ++j)
            bfr[j] = *(const bf16x8*)(&Bs[cur][(wc + j * 16 + lr) * 32 + rslot]);
#pragma unroll
        for (int i = 0; i < 4; ++i)
#pragma unroll
            for (int j = 0; j < 4; ++j)
                acc[i][j] = __builtin_amdgcn_mfma_f32_16x16x32_bf16(af[i], bfr[j], acc[i][j], 0, 0, 0);
        __builtin_amdgcn_sched_barrier(0);
        asm volatile("s_waitcnt lgkmcnt(0)" ::: "memory");
        cur = (cur + 1 == 3) ? 0 : cur + 1;
    }

    void* Cout = (SPLITK && part) ? C1 : C0;
#pragma unroll
    for (int i = 0; i < 4; ++i) {
#pragma unroll
        for (int j = 0; j < 4; ++j) {
            const int col = col0 + wc + j * 16 + lr;
            float bcol = (EPI >= 1) ? bias[col] : 0.f;
#pragma unroll
            for (int r = 0; r < 4; ++r) {
                const int row = row0 + wr + i * 16 + lg * 4 + r;
                float v = acc[i][j][r];
                if (EPI >= 1) v += bcol;
                if (EPI == 2) v = v / (1.0f + expf(-v));
                if (OUTBF) ((short*)Cout)[(size_t)row * N + col] = (short)f2bf(v);
                else       ((float*)Cout)[(size_t)row * N + col] = v;
            }
        }
    }
}

// ---------------------------------------------------------------- 256x256 bf16 GEMM
// T3-minimum 2-phase (m230-V0 structure: 682 TF reference vs 128^2's ~330).
// 8 waves (512 thr), wave = 128x64 output, BK=64, double-buffered 128KB LDS,
// 64 MFMA per wave per K-step amortize each barrier. Source-side XOR k-slot
// swizzle (involution keyed on row&7); same ascending-K accumulation order as
// gemm_bt => bit-identical results. Direct-store epilogue.
template <int EPI>
__global__ __launch_bounds__(512, 2) void gemm256(const short* __restrict__ A,
                                                  const short* __restrict__ BT,
                                                  const float* __restrict__ bias,
                                                  short* __restrict__ Cout,
                                                  int M, int N, int K) {
    __shared__ short As[2][256 * 64];
    __shared__ short Bs[2][256 * 64];
    const int t = threadIdx.x;
    const int w = t >> 6, l = t & 63;
    const int lr = l & 15, lg = l >> 4;

    // XCD-contiguous block remap (nwg % 8 == 0 required)
    const int GX = gridDim.x;
    const int nwg = GX * gridDim.y;
    int flat = blockIdx.y * GX + blockIdx.x;
    flat = (flat & 7) * (nwg >> 3) + (flat >> 3);
    const int bx = flat % GX, by = flat / GX;
    const int row0 = by * 256, col0 = bx * 256;
    const int wr = (w >> 2) * 128, wc = (w & 3) * 64;

    f32x4 acc[8][4];
#pragma unroll
    for (int i = 0; i < 8; ++i)
#pragma unroll
        for (int j = 0; j < 4; ++j) acc[i][j] = (f32x4){0.f, 0.f, 0.f, 0.f};

    // staging: 8 waves x 4 instr x 1KB = 32KB per operand per K-step.
    // chunk c = w*4+j covers rows [c*8, c*8+8); lane l -> row c*8+(l>>3),
    // LDS slot l&7; global k-slot = (l&7) ^ ((l>>3)&7)  (row&7 == (l>>3)&7).
    const int sg = (((l & 7) ^ ((l >> 3) & 7))) * 8;
    const short* Ag = A + (size_t)(row0 + w * 32 + (l >> 3)) * K + sg;
    const short* Bg = BT + (size_t)(col0 + w * 32 + (l >> 3)) * K + sg;

    const int nst = K >> 6;

    auto stage = [&](int T, int Bf) {
#pragma unroll
        for (int j = 0; j < 4; ++j) {
            GLD16(Ag + (T << 6) + (size_t)j * 8 * K, &As[Bf][(w * 4 + j) * 512]);
            GLD16(Bg + (T << 6) + (size_t)j * 8 * K, &Bs[Bf][(w * 4 + j) * 512]);
        }
    };

    stage(0, 0);
    __syncthreads();

    int cur = 0;
    for (int k = 0; k < nst; ++k) {
        if (k + 1 < nst) stage(k + 1, cur ^ 1);
        __builtin_amdgcn_s_setprio(1);
#pragma unroll
        for (int kk = 0; kk < 2; ++kk) {
            const int rs = ((kk * 4 + lg) ^ (lr & 7)) * 8;
            bf16x8 af[8], bfr[4];
#pragma unroll
            for (int i = 0; i < 8; ++i)
                af[i] = *(const bf16x8*)(&As[cur][(wr + i * 16 + lr) * 64 + rs]);
#pragma unroll
            for (int j = 0; j < 4; ++j)
                bfr[j] = *(const bf16x8*)(&Bs[cur][(wc + j * 16 + lr) * 64 + rs]);
#pragma unroll
            for (int i = 0; i < 8; ++i)
#pragma unroll
                for (int j = 0; j < 4; ++j)
                    acc[i][j] = __builtin_amdgcn_mfma_f32_16x16x32_bf16(af[i], bfr[j], acc[i][j], 0, 0, 0);
        }
        __builtin_amdgcn_s_setprio(0);
        __syncthreads();   // drains vmcnt (next tile landed) + LDS reads done
        cur ^= 1;
    }

#pragma unroll
    for (int i = 0; i < 8; ++i) {
#pragma unroll
        for (int j = 0; j < 4; ++j) {
            const int col = col0 + wc + j * 16 + lr;
            float bcol = (EPI >= 1) ? bias[col] : 0.f;
#pragma unroll
            for (int r = 0; r < 4; ++r) {
                const int row = row0 + wr + i * 16 + lg * 4 + r;
                float v = acc[i][j][r];
                if (EPI >= 1) v += bcol;
                if (EPI == 2) v = v / (1.0f + expf(-v));
                Cout[(size_t)row * N + col] = (short)f2bf(v);
            }
        }
    }
}

// ------------------------------------------------- RoPE + split + q2/k2 RMSNorm (bf16 io)
__global__ __launch_bounds__(256) void rope_kernel(const short* __restrict__ qkv,
                                                   const float* __restrict__ sigmas,
                                                   const float* __restrict__ lnq_w,
                                                   const float* __restrict__ lnq_b,
                                                   short* __restrict__ q1, short* __restrict__ q2n,
                                                   short* __restrict__ k1, short* __restrict__ k2n) {
    const int tok = blockIdx.x;            // 0..4095
    const int b = tok >> 11, s = tok & 2047;
    const int t = threadIdx.x;
    const int hh = t >> 4;                 // 0..15 (head in 2H layout)
    const int d0 = (t & 15) * 4;

    const short* qrow = qkv + (size_t)tok * 3072 + hh * 64 + d0;
    ushort4 qv = *(const ushort4*)qrow;
    ushort4 kv = *(const ushort4*)(qrow + 1024);
    float q[4] = {bf2f(qv.x), bf2f(qv.y), bf2f(qv.z), bf2f(qv.w)};
    float k[4] = {bf2f(kv.x), bf2f(kv.y), bf2f(kv.z), bf2f(kv.w)};

    if (d0 < 32) {
#pragma unroll
        for (int pr = 0; pr < 2; ++pr) {
            const int i = d0 / 2 + pr;
            float freq = (float)s * powf(10000.0f, -(float)i / 16.0f);
            float sn, c;
            sincosf(freq, &sn, &c);
            float x0 = q[2 * pr], x1 = q[2 * pr + 1];
            q[2 * pr]     = x0 * c - x1 * sn;
            q[2 * pr + 1] = x1 * c + x0 * sn;
            x0 = k[2 * pr]; x1 = k[2 * pr + 1];
            k[2 * pr]     = x0 * c - x1 * sn;
            k[2 * pr + 1] = x1 * c + x0 * sn;
        }
    }

    const int h = hh >> 1, j = hh & 1;
    const size_t obase = ((size_t)(b * H_ + h) * S_ + s) * 64 + d0;
    if (j == 0) {
        *(ushort4*)&q1[obase] = make_ushort4(f2bf(q[0]), f2bf(q[1]), f2bf(q[2]), f2bf(q[3]));
        *(ushort4*)&k1[obase] = make_ushort4(f2bf(k[0]), f2bf(k[1]), f2bf(k[2]), f2bf(k[3]));
    } else {
        float ssq_q = 0.f, ssq_k = 0.f;
#pragma unroll
        for (int i = 0; i < 4; ++i) {
            const float sg = sigmas[b * 64 + d0 + i];
            q[i] += sg; k[i] += sg;
            ssq_q += q[i] * q[i];
            ssq_k += k[i] * k[i];
        }
        for (int off = 1; off < 16; off <<= 1) {
            ssq_q += __shfl_xor(ssq_q, off, 16);
            ssq_k += __shfl_xor(ssq_k, off, 16);
        }
        const float rq = rsqrtf(ssq_q / 64.0f + 1e-8f);
        const float rk = rsqrtf(ssq_k / 64.0f + 1e-8f);
        float oq[4], ok[4];
#pragma unroll
        for (int i = 0; i < 4; ++i) {
            const float w = lnq_w[d0 + i], bb = lnq_b[d0 + i];
            oq[i] = q[i] * rq * w + bb;
            ok[i] = k[i] * rk * w + bb;
        }
        *(ushort4*)&q2n[obase] = make_ushort4(f2bf(oq[0]), f2bf(oq[1]), f2bf(oq[2]), f2bf(oq[3]));
        *(ushort4*)&k2n[obase] = make_ushort4(f2bf(ok[0]), f2bf(ok[1]), f2bf(ok[2]), f2bf(ok[3]));
    }
}

// ------------------------------------------------- softmax update (per wave, one branch)
// T13 defer-rescale: skip O-rescale when running max grows <= 8 (P bounded by e^8).
__device__ __forceinline__ void sm_update(f32x4 (&s)[4], float (&m)[4], float (&lsum)[4],
                                          f32x4 (&o)[8], short* __restrict__ Pw,
                                          const bool diag, const int qr0, const int k0,
                                          const int lr, const int lg) {
    float nm[4];
#pragma unroll
    for (int r = 0; r < 4; ++r) nm[r] = m[r];
#pragma unroll
    for (int ks = 0; ks < 4; ++ks) {
#pragma unroll
        for (int r = 0; r < 4; ++r) {
            float v = s[ks][r];
            if (diag && (k0 + ks * 16 + lr > qr0 + r)) v = -INFINITY;
            else v *= 0.125f;
            s[ks][r] = v;
            nm[r] = fmaxf(nm[r], v);
        }
    }
#pragma unroll
    for (int r = 0; r < 4; ++r) {
        nm[r] = fmaxf(nm[r], __shfl_xor(nm[r], 1));
        nm[r] = fmaxf(nm[r], __shfl_xor(nm[r], 2));
        nm[r] = fmaxf(nm[r], __shfl_xor(nm[r], 4));
        nm[r] = fmaxf(nm[r], __shfl_xor(nm[r], 8));
    }
    bool grow = false;
#pragma unroll
    for (int r = 0; r < 4; ++r) grow = grow || (nm[r] > m[r] + 8.0f);
    if (__any(grow)) {
        float al[4];
#pragma unroll
        for (int r = 0; r < 4; ++r) {
            al[r] = __expf(m[r] - nm[r]);
            m[r] = nm[r];
            lsum[r] *= al[r];
        }
#pragma unroll
        for (int es = 0; es < 8; ++es) {
#pragma unroll
            for (int r = 0; r < 4; ++r) o[es][r] *= al[r];
        }
    }
    float rs[4] = {0.f, 0.f, 0.f, 0.f};
#pragma unroll
    for (int ks = 0; ks < 4; ++ks) {
#pragma unroll
        for (int r = 0; r < 4; ++r) {
            float p = __expf(s[ks][r] - m[r]);
            rs[r] += p;
            Pw[(lg * 4 + r) * 72 + ks * 16 + lr] = (short)f2bf(p);
        }
    }
#pragma unroll
    for (int r = 0; r < 4; ++r) {
        rs[r] += __shfl_xor(rs[r], 1);
        rs[r] += __shfl_xor(rs[r], 2);
        rs[r] += __shfl_xor(rs[r], 4);
        rs[r] += __shfl_xor(rs[r], 8);
        lsum[r] += rs[r];
    }
}

// ------------------------------------------------- dual attention, split-K partials
// (round-13 staged-V config: 1024 blocks x 4 waves, QBLK=64, KVBLK=64, LDS 45KB,
// 3 blocks/CU, XCD-swizzled 2 bh/XCD. V-direct experiments (r14/r15) regressed.)
__global__ __launch_bounds__(256, 3) void attn_part(const short* __restrict__ q1g,
                                                    const short* __restrict__ q2g,
                                                    const short* __restrict__ k1g,
                                                    const short* __restrict__ k2g,
                                                    const short* __restrict__ vt,
                                                    short* __restrict__ pO0,
                                                    short* __restrict__ pO1,
                                                    float* __restrict__ pml) {
    __shared__ short Ks1[64 * 72];
    __shared__ short Ks2[64 * 72];
    __shared__ short Vt[128 * 72];
    __shared__ short Ps[4][16 * 72];   // per-wave P (reused across branches)

    const int i = blockIdx.x;            // 0..1023
    const int xcd = i & 7;
    const int slot = i >> 3;             // 0..127
    const int a = slot >> 6;             // bh within xcd
    const int j = slot & 63;
    const int qt = 31 - (j >> 1);        // LPT: big first
    const int part = j & 1;
    const int bh = xcd * 2 + a;
    const int q0 = qt * 64;
    const int t = threadIdx.x, w = t >> 6, l = t & 63;
    const int lr = l & 15, lg = l >> 4;

    const size_t kbase = (size_t)bh * S_ * 64;
    const size_t vbase = (size_t)bh * 128 * S_;

    // Q fragments (wave w owns rows q0 + w*16 .. +15)
    bf16x8 qa1[2], qa2[2];
    {
        const size_t rb = kbase + (size_t)(q0 + w * 16 + lr) * 64;
#pragma unroll
        for (int dh = 0; dh < 2; ++dh) {
            qa1[dh] = *(const bf16x8*)(q1g + rb + dh * 32 + lg * 8);
            qa2[dh] = *(const bf16x8*)(q2g + rb + dh * 32 + lg * 8);
        }
    }

    const int nkt = qt + 1, mid = (nkt + 1) >> 1;
    const int kt0 = part ? mid : 0, kt1 = part ? nkt : mid;

    float m1[4], m2[4], l1[4], l2[4];
#pragma unroll
    for (int r = 0; r < 4; ++r) { m1[r] = -1e30f; m2[r] = -1e30f; l1[r] = 0.f; l2[r] = 0.f; }
    f32x4 o1[8], o2[8];
#pragma unroll
    for (int es = 0; es < 8; ++es) { o1[es] = (f32x4){0.f,0.f,0.f,0.f}; o2[es] = (f32x4){0.f,0.f,0.f,0.f}; }

    short* Pw = &Ps[w][0];
    const int qr0 = q0 + w * 16 + lg * 4;
    const int wrow_lo = q0 + w * 16;

    const int sr = t >> 2, sc = (t & 3) * 16;   // K staging: 64 rows x 16 elems
    const int vr = t >> 1, vc = (t & 1) * 32;   // V staging: 128 rows x 32 elems

    for (int kt = kt0; kt < kt1; ++kt) {
        const int k0 = kt * 64;
        __syncthreads();   // prior tile reads done
        // stage K1,K2 [64][72] and V^T [128][72] (vectorized 16B, coalesced)
        {
            const size_t g = kbase + (size_t)(k0 + sr) * 64 + sc;
            *(bf16x8*)(Ks1 + sr * 72 + sc)     = *(const bf16x8*)(k1g + g);
            *(bf16x8*)(Ks1 + sr * 72 + sc + 8) = *(const bf16x8*)(k1g + g + 8);
            *(bf16x8*)(Ks2 + sr * 72 + sc)     = *(const bf16x8*)(k2g + g);
            *(bf16x8*)(Ks2 + sr * 72 + sc + 8) = *(const bf16x8*)(k2g + g + 8);
            const size_t gv = vbase + (size_t)vr * S_ + k0 + vc;
#pragma unroll
            for (int jj = 0; jj < 4; ++jj)
                *(bf16x8*)(Vt + vr * 72 + vc + jj * 8) = *(const bf16x8*)(vt + gv + jj * 8);
        }
        __syncthreads();

        const bool diag = (k0 + 63 > wrow_lo);

        // ---- branch 1
        {
            f32x4 s[4];
#pragma unroll
            for (int ks = 0; ks < 4; ++ks) s[ks] = (f32x4){0.f,0.f,0.f,0.f};
            __builtin_amdgcn_s_setprio(1);
#pragma unroll
            for (int ks = 0; ks < 4; ++ks)
#pragma unroll
                for (int dh = 0; dh < 2; ++dh) {
                    bf16x8 kf = *(const bf16x8*)(Ks1 + (ks * 16 + lr) * 72 + dh * 32 + lg * 8);
                    s[ks] = __builtin_amdgcn_mfma_f32_16x16x32_bf16(qa1[dh], kf, s[ks], 0, 0, 0);
                }
            __builtin_amdgcn_s_setprio(0);
            sm_update(s, m1, l1, o1, Pw, diag, qr0, k0, lr, lg);
            __builtin_amdgcn_s_setprio(1);
#pragma unroll
            for (int kb = 0; kb < 2; ++kb) {
                bf16x8 pf = *(const bf16x8*)(Pw + lr * 72 + kb * 32 + lg * 8);
#pragma unroll
                for (int es = 0; es < 8; ++es) {
                    bf16x8 vf = *(const bf16x8*)(Vt + (es * 16 + lr) * 72 + kb * 32 + lg * 8);
                    o1[es] = __builtin_amdgcn_mfma_f32_16x16x32_bf16(pf, vf, o1[es], 0, 0, 0);
                }
            }
            __builtin_amdgcn_s_setprio(0);
        }
        // ---- branch 2
        {
            f32x4 s[4];
#pragma unroll
            for (int ks = 0; ks < 4; ++ks) s[ks] = (f32x4){0.f,0.f,0.f,0.f};
            __builtin_amdgcn_s_setprio(1);
#pragma unroll
            for (int ks = 0; ks < 4; ++ks)
#pragma unroll
                for (int dh = 0; dh < 2; ++dh) {
                    bf16x8 kf = *(const bf16x8*)(Ks2 + (ks * 16 + lr) * 72 + dh * 32 + lg * 8);
                    s[ks] = __builtin_amdgcn_mfma_f32_16x16x32_bf16(qa2[dh], kf, s[ks], 0, 0, 0);
                }
            __builtin_amdgcn_s_setprio(0);
            sm_update(s, m2, l2, o2, Pw, diag, qr0, k0, lr, lg);
            __builtin_amdgcn_s_setprio(1);
#pragma unroll
            for (int kb = 0; kb < 2; ++kb) {
                bf16x8 pf = *(const bf16x8*)(Pw + lr * 72 + kb * 32 + lg * 8);
#pragma unroll
                for (int es = 0; es < 8; ++es) {
                    bf16x8 vf = *(const bf16x8*)(Vt + (es * 16 + lr) * 72 + kb * 32 + lg * 8);
                    o2[es] = __builtin_amdgcn_mfma_f32_16x16x32_bf16(pf, vf, o2[es], 0, 0, 0);
                }
            }
            __builtin_amdgcn_s_setprio(0);
        }
    }

    // store partials: packed 2xbf16 uints, wave-fragment layout, fully coalesced.
    {
        uint32_t* pO = (uint32_t*)(part ? pO1 : pO0);
        const size_t wb = (((size_t)bh * 32 + qt) * 4 + w) * 2048;
#pragma unroll
        for (int r = 0; r < 4; ++r) {
#pragma unroll
            for (int u = 0; u < 4; ++u) {
                uint32_t v1 = (uint32_t)f2bf(o1[2 * u][r]) | ((uint32_t)f2bf(o1[2 * u + 1][r]) << 16);
                pO[wb + (size_t)((r * 2 + 0) * 4 + u) * 64 + l] = v1;
                uint32_t v2 = (uint32_t)f2bf(o2[2 * u][r]) | ((uint32_t)f2bf(o2[2 * u + 1][r]) << 16);
                pO[wb + (size_t)((r * 2 + 1) * 4 + u) * 64 + l] = v2;
            }
        }
    }
    if (lr == 0) {
#pragma unroll
        for (int r = 0; r < 4; ++r) {
            const int q = q0 + w * 16 + lg * 4 + r;
            float4 v = make_float4(m1[r], l1[r], m2[r], l2[r]);
            *(float4*)&pml[(((size_t)part * 16 + bh) * S_ + q) * 4] = v;
        }
    }
}

// ------------------------------------------------- combine partials + diff + RMSNorm
__global__ __launch_bounds__(256) void attn_combine(const short* __restrict__ pO0,
                                                    const short* __restrict__ pO1,
                                                    const float* __restrict__ pml,
                                                    const float* __restrict__ lamp,
                                                    const float* __restrict__ ln_w,
                                                    const float* __restrict__ ln_b,
                                                    short* __restrict__ arms) {
    const int tok = blockIdx.x;           // 0..4095
    const int b = tok >> 11, q = tok & 2047;
    const int t = threadIdx.x;
    const int h = t >> 5, ln32 = t & 31, e0 = ln32 * 4;
    const int bh = b * H_ + h;
    const float lam = lamp[0];

    float4 mla = *(const float4*)&pml[(((size_t)0 * 16 + bh) * S_ + q) * 4];
    float4 mlb = *(const float4*)&pml[(((size_t)1 * 16 + bh) * S_ + q) * 4];

    const float m1 = fmaxf(mla.x, mlb.x);
    const float aa1 = __expf(mla.x - m1), ab1 = __expf(mlb.x - m1);
    const float il1 = 1.0f / (aa1 * mla.y + ab1 * mlb.y);
    const float m2 = fmaxf(mla.z, mlb.z);
    const float aa2 = __expf(mla.z - m2), ab2 = __expf(mlb.z - m2);
    const float il2 = 1.0f / (aa2 * mla.w + ab2 * mlb.w);

    // decode packed wave-fragment layout (QBLK=64: qt=q>>6, w=(q>>4)&3)
    const int qt = q >> 6, w = (q >> 4) & 3, lg = (q >> 2) & 3, r = q & 3;
    const int es = ln32 >> 2, u = es >> 1, half = es & 1;
    const int lane0 = lg * 16 + (ln32 & 3) * 4;
    const size_t wb = (((size_t)bh * 32 + qt) * 4 + w) * 2048;
    const uint32_t* P0 = (const uint32_t*)pO0;
    const uint32_t* P1 = (const uint32_t*)pO1;
    const uint4 a1  = *(const uint4*)&P0[wb + (size_t)((r * 2 + 0) * 4 + u) * 64 + lane0];
    const uint4 b1v = *(const uint4*)&P1[wb + (size_t)((r * 2 + 0) * 4 + u) * 64 + lane0];
    const uint4 a2  = *(const uint4*)&P0[wb + (size_t)((r * 2 + 1) * 4 + u) * 64 + lane0];
    const uint4 b2v = *(const uint4*)&P1[wb + (size_t)((r * 2 + 1) * 4 + u) * 64 + lane0];
    const int sh = 16 * half;

    float comb[4]; float ssq = 0.f;
    {
        const uint32_t aw1[4] = {a1.x, a1.y, a1.z, a1.w};
        const uint32_t bw1[4] = {b1v.x, b1v.y, b1v.z, b1v.w};
        const uint32_t aw2[4] = {a2.x, a2.y, a2.z, a2.w};
        const uint32_t bw2[4] = {b2v.x, b2v.y, b2v.z, b2v.w};
#pragma unroll
        for (int i = 0; i < 4; ++i) {
            const float O1 = (aa1 * bf2f((unsigned short)(aw1[i] >> sh)) +
                              ab1 * bf2f((unsigned short)(bw1[i] >> sh))) * il1;
            const float O2 = (aa2 * bf2f((unsigned short)(aw2[i] >> sh)) +
                              ab2 * bf2f((unsigned short)(bw2[i] >> sh))) * il2;
            const float c = O1 - lam * O2;
            comb[i] = c; ssq += c * c;
        }
    }
    for (int off = 1; off < 32; off <<= 1) ssq += __shfl_xor(ssq, off, 32);
    const float rms = rsqrtf(ssq / 128.0f + 1e-8f);

    ushort4 o;
    unsigned short* op = (unsigned short*)&o;
#pragma unroll
    for (int i = 0; i < 4; ++i) {
        const int e = e0 + i;
        op[i] = f2bf((comb[i] * rms * ln_w[e] + ln_b[e]) * ONE_MINUS_LI);
    }
    *(ushort4*)&arms[(size_t)tok * 1024 + h * 128 + e0] = o;
}

// -------------------------- add_ln1: h_bf = bf16( LN(a0 + a1 + x) )
__global__ __launch_bounds__(256) void add_ln1_kernel(const float* __restrict__ A0,
                                                      const float* __restrict__ A1,
                                                      const float* __restrict__ X,
                                                      const float* __restrict__ w,
                                                      const float* __restrict__ bvec,
                                                      short* __restrict__ out_bf) {
    const int row = blockIdx.x;
    const int t = threadIdx.x;
    __shared__ float red[4];

    float4 a0 = *(const float4*)&A0[(size_t)row * 1024 + t * 4];
    float4 a1 = *(const float4*)&A1[(size_t)row * 1024 + t * 4];
    float4 xv = *(const float4*)&X[(size_t)row * 1024 + t * 4];
    float v[4] = {a0.x + a1.x + xv.x, a0.y + a1.y + xv.y,
                  a0.z + a1.z + xv.z, a0.w + a1.w + xv.w};

    float s = v[0] + v[1] + v[2] + v[3];
    for (int off = 1; off < 64; off <<= 1) s += __shfl_xor(s, off);
    if ((t & 63) == 0) red[t >> 6] = s;
    __syncthreads();
    const float mean = (red[0] + red[1] + red[2] + red[3]) * (1.0f / 1024.0f);

    float sq = 0.f;
#pragma unroll
    for (int i = 0; i < 4; ++i) { const float d = v[i] - mean; sq += d * d; }
    __syncthreads();
    for (int off = 1; off < 64; off <<= 1) sq += __shfl_xor(sq, off);
    if ((t & 63) == 0) red[t >> 6] = sq;
    __syncthreads();
    const float var = (red[0] + red[1] + red[2] + red[3]) * (1.0f / 1024.0f);
    const float rstd = rsqrtf(var + 1e-5f);

    ushort4 o;
    unsigned short* op = (unsigned short*)&o;
#pragma unroll
    for (int i = 0; i < 4; ++i)
        op[i] = f2bf((v[i] - mean) * rstd * w[t * 4 + i] + bvec[t * 4 + i]);
    *(ushort4*)&out_bf[(size_t)row * 1024 + t * 4] = o;
}

// -------------------------- add_ln2: out = LN(f0 + f1 + bias + h_bf)  (f32 out)
__global__ __launch_bounds__(256) void add_ln2_kernel(const float* __restrict__ F0,
                                                      const float* __restrict__ F1,
                                                      const float* __restrict__ bias,
                                                      const short* __restrict__ Hbf,
                                                      const float* __restrict__ w,
                                                      const float* __restrict__ bvec,
                                                      float* __restrict__ out) {
    const int row = blockIdx.x;
    const int t = threadIdx.x;
    __shared__ float red[4];

    float4 f0 = *(const float4*)&F0[(size_t)row * 1024 + t * 4];
    float4 f1 = *(const float4*)&F1[(size_t)row * 1024 + t * 4];
    float4 bv = *(const float4*)&bias[t * 4];
    ushort4 hv = *(const ushort4*)&Hbf[(size_t)row * 1024 + t * 4];
    float v[4] = {f0.x + f1.x + bv.x + bf2f(hv.x), f0.y + f1.y + bv.y + bf2f(hv.y),
                  f0.z + f1.z + bv.z + bf2f(hv.z), f0.w + f1.w + bv.w + bf2f(hv.w)};

    float s = v[0] + v[1] + v[2] + v[3];
    for (int off = 1; off < 64; off <<= 1) s += __shfl_xor(s, off);
    if ((t & 63) == 0) red[t >> 6] = s;
    __syncthreads();
    const float mean = (red[0] + red[1] + red[2] + red[3]) * (1.0f / 1024.0f);

    float sq = 0.f;
#pragma unroll
    for (int i = 0; i < 4; ++i) { const float d = v[i] - mean; sq += d * d; }
    __syncthreads();
    for (int off = 1; off < 64; off <<= 1) sq += __shfl_xor(sq, off);
    if ((t & 63) == 0) red[t >> 6] = sq;
    __syncthreads();
    const float var = (red[0] + red[1] + red[2] + red[3]) * (1.0f / 1024.0f);
    const float rstd = rsqrtf(var + 1e-5f);

    float o[4];
#pragma unroll
    for (int i = 0; i < 4; ++i)
        o[i] = (v[i] - mean) * rstd * w[t * 4 + i] + bvec[t * 4 + i];
    *(float4*)&out[(size_t)row * 1024 + t * 4] = make_float4(o[0], o[1], o[2], o[3]);
}

// ---------------------------------------------------------------- launch
extern "C" void kernel_launch(void* const* d_in, const int* in_sizes, int n_in,
                              void* d_out, int out_size, void* d_ws, size_t ws_size,
                              hipStream_t stream) {
    const float* x      = (const float*)d_in[0];
    const float* sigmas = (const float*)d_in[1];
    const float* w_qkv  = (const float*)d_in[2];
    const float* w_out  = (const float*)d_in[3];
    const float* lq1    = (const float*)d_in[4];
    const float* lk1    = (const float*)d_in[5];
    const float* lq2    = (const float*)d_in[6];
    const float* lk2    = (const float*)d_in[7];
    const float* ln_w   = (const float*)d_in[8];
    const float* ln_b   = (const float*)d_in[9];
    const float* lnq_w  = (const float*)d_in[10];
    const float* lnq_b  = (const float*)d_in[11];
    const float* ln1_w  = (const float*)d_in[12];
    const float* ln1_b  = (const float*)d_in[13];
    const float* ln2_w  = (const float*)d_in[14];
    const float* ln2_b  = (const float*)d_in[15];
    const float* w1     = (const float*)d_in[16];
    const float* b1     = (const float*)d_in[17];
    const float* w2     = (const float*)d_in[18];
    const float* b2     = (const float*)d_in[19];

    char* ws = (char*)d_ws;
    // layout (bytes):
    short* x_bf    = (short*)(ws + 0);            // 8,388,608 ; reused: vt, then h_bf
    short* vt      = (short*)(ws + 0);
    short* h_bf    = (short*)(ws + 0);
    short* w_qkvT  = (short*)(ws + 8388608);      // 6,291,456
    short* w_outT  = (short*)(ws + 14680064);     // 2,097,152
    short* w1T     = (short*)(ws + 16777216);     // 8,388,608
    short* w2T     = (short*)(ws + 25165824);     // 8,388,608
    short* qkv_bf  = (short*)(ws + 33554432);     // 25,165,824 (dead after rope+vtrans)
    short* pO0     = (short*)(ws + 33554432);     // 16,777,216
    float* pml     = (float*)(ws + 50331648);     // 1,048,576
    float* a_p0    = (float*)(ws + 33554432);     // 16,777,216 (after combine)
    short* q1      = (short*)(ws + 58720256);     // 4x 4,194,304 -> ends 75,497,472
    short* q2n     = (short*)(ws + 62914560);
    short* k1      = (short*)(ws + 67108864);
    short* k2n     = (short*)(ws + 71303168);
    float* a_p1    = (float*)(ws + 58720256);     // 16,777,216 (after attn)
    short* pO1     = (short*)(ws + 75497472);     // 16,777,216 -> ends 92,274,688
    short* arms    = (short*)(ws + 92274688);     // 8,388,608 -> ends 100,663,296
    short* ffh     = (short*)(ws + 33554432);     // 33,554,432 (after add_ln1) -> 67,108,864
    float* ff_p0   = (float*)(ws + 67108864);     // 16,777,216 -> 83,886,080
    float* ff_p1   = (float*)(ws + 83886080);     // 16,777,216 -> 100,663,296
    float* lam     = (float*)(ws + 100663296);

    // 1. lambda + fused prep (weight transposes + x convert)
    lam_kernel<<<1, 64, 0, stream>>>(lq1, lk1, lq2, lk2, lam);
    prep_kernel<<<16384, 256, 0, stream>>>(x, w_qkv, w_out, w1, w2,
                                           x_bf, w_qkvT, w_outT, w1T, w2T);

    // 2. qkv = x @ w_qkv -> bf16  (256^2 tile: grid 12x16 = 192 blocks)
    gemm256<0><<<dim3(12, 16), 512, 0, stream>>>(x_bf, w_qkvT, nullptr,
                                                 qkv_bf, NT_, 3072, 1024);

    // 3. rope + split + q2/k2 rmsnorm ; V transpose (x_bf dead now)
    rope_kernel<<<NT_, 256, 0, stream>>>(qkv_bf, sigmas, lnq_w, lnq_b, q1, q2n, k1, k2n);
    vtrans_kernel<<<dim3(S_ / 32, 4, 16), 256, 0, stream>>>(qkv_bf, vt);

    // 4. dual attention split-K partials + combine
    attn_part<<<1024, 256, 0, stream>>>(q1, q2n, k1, k2n, vt, pO0, pO1, pml);
    attn_combine<<<NT_, 256, 0, stream>>>(pO0, pO1, pml, lam, ln_w, ln_b, arms);

    // 5. a = arms @ w_out, split-K x2 -> f32 partials (grid 8x64 = 512 blocks)
    gemm_bt<0, 0, 1><<<dim3(8, 64), 256, 0, stream>>>(arms, w_outT, nullptr,
                                                      a_p0, a_p1, NT_, 1024, 1024, 512);

    // 6. h_bf = bf16(LN(a0 + a1 + x))
    add_ln1_kernel<<<NT_, 256, 0, stream>>>(a_p0, a_p1, x, ln1_w, ln1_b, h_bf);

    // 7. ffh = silu(h @ w1 + b1) -> bf16  (256^2 tile: grid 16x16 = 256 blocks)
    gemm256<2><<<dim3(16, 16), 512, 0, stream>>>(h_bf, w1T, b1,
                                                 ffh, NT_, 4096, 1024);

    // 8. ff = ffh @ w2, split-K x2 -> f32 partials (grid 8x64 = 512 blocks)
    gemm_bt<0, 0, 1><<<dim3(8, 64), 256, 0, stream>>>(ffh, w2T, nullptr,
                                                      ff_p0, ff_p1, NT_, 1024, 4096, 2048);

    // 9. out = LN(ff0 + ff1 + b2 + h)
    add_ln2_kernel<<<NT_, 256, 0, stream>>>(ff_p0, ff_p1, b2, h_bf, ln2_w, ln2_b,
                                            (float*)d_out);
}